// Round 1
// baseline (432.683 us; speedup 1.0000x reference)
//
#include <hip/hip_runtime.h>
#include <hip/hip_bf16.h>
#include <math.h>

typedef __hip_bfloat16 bf16;

#define D_MODEL 1024
#define D_INNER 2048
#define NTOK    4096   // B*L
#define SEQ     2048
#define BSZ     2
#define DSTATE  16
#define DTRANK  64
#define NCH     64
#define CHLEN   32     // SEQ / NCH
#define NPAIR   4096   // BSZ * D_INNER
#define XDS     128    // xdbl row stride (fp32), padded from 96

__device__ __forceinline__ float b2f(bf16 v) { return __bfloat162float(v); }
__device__ __forceinline__ bf16  f2b(float v) { return __float2bfloat16(v); }
__device__ __forceinline__ short f2bs(float v) {
    bf16 h = __float2bfloat16(v);
    short s; __builtin_memcpy(&s, &h, 2); return s;
}

typedef __attribute__((ext_vector_type(8))) short short8;
typedef __attribute__((ext_vector_type(4))) float f32x4;

__device__ __forceinline__ void async_copy16(const void* g, void* l) {
    __builtin_amdgcn_global_load_lds(
        (const __attribute__((address_space(1))) unsigned int*)g,
        (__attribute__((address_space(3))) unsigned int*)l,
        16, 0, 0);
}

// ---------------------------------------------------------------- fused prep
// blocks [0,4096): LayerNorm; [4096,8192): f2b W_in; [8192,8448): prep xpw;
// [8448,8576): f2b dtw; [8576,9088): zero xdbl. Uniform branch per block.
__global__ void k_prep(const float* __restrict__ x, const float* __restrict__ g,
                       const float* __restrict__ b, bf16* __restrict__ xn,
                       const float* __restrict__ W_in, short* __restrict__ wInb,
                       const float* __restrict__ xpw, short* __restrict__ xpwb,
                       const float* __restrict__ dtw, short* __restrict__ dtwb,
                       float* __restrict__ xdbl) {
    int bid = blockIdx.x;
    int tid = threadIdx.x;
    if (bid < 4096) {                       // ---- LayerNorm, one block per token
        int t = bid;
        const float* row = x + (size_t)t * D_MODEL;
        float v[4];
        float s = 0.f, q = 0.f;
#pragma unroll
        for (int i = 0; i < 4; ++i) {
            int idx = tid + i * 256;
            v[i] = row[idx];
            s += v[i]; q += v[i] * v[i];
        }
        __shared__ float sh_s[256], sh_q[256];
        sh_s[tid] = s; sh_q[tid] = q;
        __syncthreads();
        for (int o = 128; o > 0; o >>= 1) {
            if (tid < o) { sh_s[tid] += sh_s[tid + o]; sh_q[tid] += sh_q[tid + o]; }
            __syncthreads();
        }
        float mu  = sh_s[0] * (1.f / D_MODEL);
        float var = sh_q[0] * (1.f / D_MODEL) - mu * mu;
        float rs  = rsqrtf(var + 1e-5f);
#pragma unroll
        for (int i = 0; i < 4; ++i) {
            int idx = tid + i * 256;
            float o = (v[i] - mu) * rs * g[idx] + b[idx];
            xn[(size_t)t * D_MODEL + idx] = f2b(o);
        }
    } else if (bid < 8192) {                // ---- f2b W_in (float4 per thread)
        int i = (bid - 4096) * 256 + tid;
        float4 v = reinterpret_cast<const float4*>(W_in)[i];
        short4 o;
        o.x = f2bs(v.x); o.y = f2bs(v.y); o.z = f2bs(v.z); o.w = f2bs(v.w);
        reinterpret_cast<short4*>(wInb)[i] = o;
    } else if (bid < 8448) {                // ---- xpw 96x2048 -> padded 128x2048 bf16
        int i = (bid - 8192) * 256 + tid;
        int row = i >> 9;
        short4 o;
        if (row < 96) {
            float4 v = reinterpret_cast<const float4*>(xpw)[i];
            o.x = f2bs(v.x); o.y = f2bs(v.y); o.z = f2bs(v.z); o.w = f2bs(v.w);
        } else { o.x = o.y = o.z = o.w = 0; }
        reinterpret_cast<short4*>(xpwb)[i] = o;
    } else if (bid < 8576) {                // ---- f2b dtw
        int i = (bid - 8448) * 256 + tid;
        float4 v = reinterpret_cast<const float4*>(dtw)[i];
        short4 o;
        o.x = f2bs(v.x); o.y = f2bs(v.y); o.z = f2bs(v.z); o.w = f2bs(v.w);
        reinterpret_cast<short4*>(dtwb)[i] = o;
    } else {                                // ---- zero xdbl
        int i = (bid - 8576) * 256 + tid;
        reinterpret_cast<float4*>(xdbl)[i] = (float4){0.f, 0.f, 0.f, 0.f};
    }
}

// ---------------------------------------------------------------- fp32 -> bf16 convert
__global__ void k_f2b(const float* __restrict__ in, short* __restrict__ out) {
    int i = blockIdx.x * 256 + threadIdx.x;
    float4 v = reinterpret_cast<const float4*>(in)[i];
    short4 o;
    o.x = f2bs(v.x); o.y = f2bs(v.y); o.z = f2bs(v.z); o.w = f2bs(v.w);
    reinterpret_cast<short4*>(out)[i] = o;
}

// --------------------------------------------- dr = xdbl[:, 0:64] -> bf16 (4096x64)
__global__ void k_extract_dr(const float* __restrict__ xdbl, short* __restrict__ drb) {
    int i = blockIdx.x * 256 + threadIdx.x;
    int t = i >> 4;
    int jg = (i & 15) * 4;
    float4 v = *reinterpret_cast<const float4*>(&xdbl[(size_t)t * XDS + jg]);
    short4 o;
    o.x = f2bs(v.x); o.y = f2bs(v.y); o.z = f2bs(v.z); o.w = f2bs(v.w);
    *reinterpret_cast<short4*>(&drb[(size_t)t * DTRANK + jg]) = o;
}

// ---------------------------------------------------------------- MFMA GEMM (NT)
// 128 x NT block tile (NT = 128 or 64), BK=32, R8 double-buffered single-barrier
// K-loop, R7 XOR bank swizzle. M always 4096.
// mode 0: split at D_INNER -> Cf fp32 / Cz bf16   (in-proj)
// mode 1: Cout = acc + res (fp32, residual)
// mode 2: atomicAdd(Cf, acc)                      (xproj, split-K via blockIdx.z)
// mode 3: Cf = softplus(acc + bias[col]) fp32     (delta)
// mode 4: Cf[z*M*N + row*N + col] = acc           (split-K partials, no atomics)
#define GBK 32
template<int NT>
__global__ __launch_bounds__(256) void k_gemm_mfma(
    const short* __restrict__ A, const short* __restrict__ Bw,
    int N, int K, int mode,
    float* __restrict__ Cf, bf16* __restrict__ Cz,
    const float* __restrict__ res, float* __restrict__ Cout,
    const float* __restrict__ bias)
{
    constexpr int ABUF = 128 * GBK;            // shorts per A buffer (8 KB)
    constexpr int BBUF = NT * GBK;             // shorts per B buffer
    constexpr int AF   = (NT == 128) ? 4 : 2;  // row frags per wave
    __shared__ short As[2 * ABUF];
    __shared__ short Bs[2 * BBUF];
    const int tid  = threadIdx.x;
    const int lane = tid & 63;
    const int wave = tid >> 6;
    const int rowbase = (NT == 128) ? (wave >> 1) * 64 : wave * 32;
    const int colbase = (NT == 128) ? (wave & 1) * 64 : 0;
    const int m0 = blockIdx.y * 128;
    const int n0 = blockIdx.x * NT;
    const int lm = lane & 15;
    const int koff = (((lane >> 4) ^ ((lane >> 1) & 3)) * 8);

    const int srow = tid >> 2;                              // 0..63
    const int skc  = (((tid & 3) ^ ((tid >> 3) & 3)) * 8);  // swizzled source chunk
    const size_t a_off0 = (size_t)(m0 + srow) * K + skc;
    const size_t a_off1 = (size_t)(m0 + srow + 64) * K + skc;
    const size_t b_off0 = (size_t)(n0 + srow) * K + skc;
    size_t b_off1 = 0;
    if constexpr (NT == 128) b_off1 = (size_t)(n0 + srow + 64) * K + skc;

    f32x4 acc[AF][4];
#pragma unroll
    for (int i = 0; i < AF; ++i)
#pragma unroll
        for (int j = 0; j < 4; ++j)
            acc[i][j] = (f32x4){0.f, 0.f, 0.f, 0.f};

    const int kchunk = K / gridDim.z;
    const int kbeg = blockIdx.z * kchunk;
    const int kend = kbeg + kchunk;

    // prologue: tile 0 into buffer 0
    {
        char* aD = (char*)As + tid * 16;
        char* bD = (char*)Bs + tid * 16;
        async_copy16(A + a_off0 + kbeg, aD);
        async_copy16(A + a_off1 + kbeg, aD + 4096);
        async_copy16(Bw + b_off0 + kbeg, bD);
        if constexpr (NT == 128) async_copy16(Bw + b_off1 + kbeg, bD + 4096);
    }

    int cur = 0;
    for (int k0 = kbeg; k0 < kend; k0 += GBK) {
        __syncthreads();   // buf[cur] ready; compute on buf[cur^1] done
        int k1 = k0 + GBK;
        if (k1 < kend) {
            int nxt = cur ^ 1;
            char* aD = (char*)As + nxt * (ABUF * 2) + tid * 16;
            char* bD = (char*)Bs + nxt * (BBUF * 2) + tid * 16;
            async_copy16(A + a_off0 + k1, aD);
            async_copy16(A + a_off1 + k1, aD + 4096);
            async_copy16(Bw + b_off0 + k1, bD);
            if constexpr (NT == 128) async_copy16(Bw + b_off1 + k1, bD + 4096);
        }

        const short* Ab = As + cur * ABUF;
        const short* Bb = Bs + cur * BBUF;
        short8 af[AF], bf[4];
#pragma unroll
        for (int t = 0; t < AF; ++t)
            af[t] = *reinterpret_cast<const short8*>(&Ab[(rowbase + t * 16 + lm) * GBK + koff]);
#pragma unroll
        for (int t = 0; t < 4; ++t)
            bf[t] = *reinterpret_cast<const short8*>(&Bb[(colbase + t * 16 + lm) * GBK + koff]);
#pragma unroll
        for (int tm = 0; tm < AF; ++tm)
#pragma unroll
            for (int tn = 0; tn < 4; ++tn)
                acc[tm][tn] = __builtin_amdgcn_mfma_f32_16x16x32_bf16(
                    af[tm], bf[tn], acc[tm][tn], 0, 0, 0);
        cur ^= 1;
    }

    const int rq = (lane >> 4) * 4;
#pragma unroll
    for (int tm = 0; tm < AF; ++tm) {
#pragma unroll
        for (int tn = 0; tn < 4; ++tn) {
            f32x4 v = acc[tm][tn];
            int col = n0 + colbase + tn * 16 + lm;
#pragma unroll
            for (int r = 0; r < 4; ++r) {
                int row = m0 + rowbase + tm * 16 + rq + r;
                float val = v[r];
                if (mode == 0) {
                    if (col < D_INNER) Cf[(size_t)row * D_INNER + col] = val;
                    else               Cz[(size_t)row * D_INNER + (col - D_INNER)] = f2b(val);
                } else if (mode == 1) {
                    Cout[(size_t)row * N + col] = val + res[(size_t)row * N + col];
                } else if (mode == 2) {
                    atomicAdd(&Cf[(size_t)row * N + col], val);
                } else if (mode == 3) {
                    float a = val + bias[col];
                    float sp = (a > 20.f) ? a : log1pf(expf(a));
                    Cf[(size_t)row * N + col] = sp;
                } else {
                    Cf[(size_t)blockIdx.z * 4096 * N + (size_t)row * N + col] = val;
                }
            }
        }
    }
}

// ------------------------------------------------- out = x + P0 + P1 (out-proj reduce)
__global__ void k_reduce_out(const float* __restrict__ x, const float* __restrict__ P,
                             float* __restrict__ out) {
    int i = blockIdx.x * 256 + threadIdx.x;
    float4 a = reinterpret_cast<const float4*>(x)[i];
    float4 p = reinterpret_cast<const float4*>(P)[i];
    float4 q = reinterpret_cast<const float4*>(P + (size_t)4096 * 1024)[i];
    float4 o;
    o.x = a.x + p.x + q.x; o.y = a.y + p.y + q.y;
    o.z = a.z + p.z + q.z; o.w = a.w + p.w + q.w;
    reinterpret_cast<float4*>(out)[i] = o;
}

// ------------------------------------------------- causal depthwise conv + SiLU
__global__ void k_conv(const float* __restrict__ xc, const float* __restrict__ cw,
                       const float* __restrict__ cb, bf16* __restrict__ xcs) {
    size_t idx = (size_t)blockIdx.x * blockDim.x + threadIdx.x;
    int d = (int)(idx & (D_INNER - 1));
    int l = (int)((idx >> 11) & (SEQ - 1));
    float w0 = cw[d * 4 + 0], w1 = cw[d * 4 + 1];
    float w2 = cw[d * 4 + 2], w3 = cw[d * 4 + 3];
    const float* base = xc + idx;
    float acc = cb[d] + w3 * base[0];
    if (l >= 1) acc += w2 * base[-(int)D_INNER];
    if (l >= 2) acc += w1 * base[-2 * (int)D_INNER];
    if (l >= 3) acc += w0 * base[-3 * (int)D_INNER];
    xcs[idx] = f2b(acc / (1.f + __expf(-acc)));   // silu
}

// ------------------------------------------------- scan pass A: per-chunk partials
__global__ __launch_bounds__(256) void k_scan_partialB(
    const float* __restrict__ delta, const bf16* __restrict__ xcs,
    const float* __restrict__ xdbl, const float* __restrict__ A_log,
    bf16* __restrict__ chs, float* __restrict__ sumdl)
{
    __shared__ float Bsh[CHLEN][16];
    const int tid = threadIdx.x;
    const int d = blockIdx.x * 256 + tid;
    const int chunk = blockIdx.y;
    const int b = blockIdx.z;
    const size_t tbase = (size_t)b * SEQ + (size_t)chunk * CHLEN;

    if (tid < 128) {
        int t = tid >> 2, j = (tid & 3) * 4;
        float4 v = *reinterpret_cast<const float4*>(&xdbl[(tbase + t) * XDS + 64 + j]);
        *reinterpret_cast<float4*>(&Bsh[t][j]) = v;
    }
    float An[16];
#pragma unroll
    for (int j = 0; j < 4; ++j) {
        float4 v = *reinterpret_cast<const float4*>(&A_log[(size_t)d * DSTATE + j * 4]);
        An[j * 4 + 0] = -__expf(v.x); An[j * 4 + 1] = -__expf(v.y);
        An[j * 4 + 2] = -__expf(v.z); An[j * 4 + 3] = -__expf(v.w);
    }
    __syncthreads();

    float s[16];
#pragma unroll
    for (int n = 0; n < 16; ++n) s[n] = 0.f;
    float sd = 0.f;
    for (int t = 0; t < CHLEN; ++t) {
        size_t gt = tbase + t;
        float dl = delta[gt * D_INNER + d];
        float u  = b2f(xcs[gt * D_INNER + d]);
        float dlu = dl * u;
        sd += dl;
#pragma unroll
        for (int n = 0; n < 16; ++n) {
            float dA = __expf(dl * An[n]);
            s[n] = fmaf(dA, s[n], dlu * Bsh[t][n]);
        }
    }
    const int pair = b * D_INNER + d;
    bf16* co = chs + ((size_t)pair * NCH + chunk) * DSTATE;
#pragma unroll
    for (int n = 0; n < 16; ++n) co[n] = f2b(s[n]);
    sumdl[(size_t)pair * NCH + chunk] = sd;
}

// ------------------------------------------------- scan pass B: chunk-prefix combine
// sst ALIASES chs: read chunk-sum before writing entry state (same thread+element).
__global__ void k_scan_combineB(const bf16* __restrict__ chs, const float* __restrict__ sumdl,
                                const float* __restrict__ A_log, bf16* __restrict__ sst) {
    int idx = blockIdx.x * 256 + threadIdx.x;
    int pair = idx >> 4;
    int n = idx & 15;
    int d = pair & (D_INNER - 1);
    float An = -__expf(A_log[(size_t)d * DSTATE + n]);
    float s = 0.f;
    for (int c = 0; c < NCH; ++c) {
        size_t o = ((size_t)pair * NCH + c) * DSTATE + n;
        float loc = b2f(chs[o]);
        float ap = __expf(An * sumdl[(size_t)pair * NCH + c]);
        sst[o] = f2b(s);
        s = fmaf(ap, s, loc);
    }
}

// ------------------------------------------------- scan pass C: final y + gate
// yf aliases zbuf elementwise (same-thread read-then-write).
__global__ __launch_bounds__(256) void k_scan_finalB(
    const float* __restrict__ delta, const bf16* __restrict__ xcs,
    const float* __restrict__ xdbl, const bf16* __restrict__ zbuf,
    const float* __restrict__ A_log, const float* __restrict__ Dp,
    const bf16* __restrict__ sst, bf16* __restrict__ yf)
{
    __shared__ float BC[CHLEN][32];   // [t][0:16]=B, [t][16:32]=C
    const int tid = threadIdx.x;
    const int d = blockIdx.x * 256 + tid;
    const int chunk = blockIdx.y;
    const int b = blockIdx.z;
    const size_t tbase = (size_t)b * SEQ + (size_t)chunk * CHLEN;

    {
        int t = tid >> 3, j = (tid & 7) * 4;
        float4 v = *reinterpret_cast<const float4*>(&xdbl[(tbase + t) * XDS + 64 + j]);
        *reinterpret_cast<float4*>(&BC[t][j]) = v;
    }
    float An[16];
#pragma unroll
    for (int j = 0; j < 4; ++j) {
        float4 v = *reinterpret_cast<const float4*>(&A_log[(size_t)d * DSTATE + j * 4]);
        An[j * 4 + 0] = -__expf(v.x); An[j * 4 + 1] = -__expf(v.y);
        An[j * 4 + 2] = -__expf(v.z); An[j * 4 + 3] = -__expf(v.w);
    }
    const int pair = b * D_INNER + d;
    float s[16];
    const bf16* so = sst + ((size_t)pair * NCH + chunk) * DSTATE;
#pragma unroll
    for (int n = 0; n < 16; ++n) s[n] = b2f(so[n]);
    const float Dv = Dp[d];
    __syncthreads();

    for (int t = 0; t < CHLEN; ++t) {
        size_t gt = tbase + t;
        float dl = delta[gt * D_INNER + d];
        float u  = b2f(xcs[gt * D_INNER + d]);
        float dlu = dl * u;
        float y = 0.f;
#pragma unroll
        for (int n = 0; n < 16; ++n) {
            float dA = __expf(dl * An[n]);
            s[n] = fmaf(dA, s[n], dlu * BC[t][n]);
            y = fmaf(s[n], BC[t][16 + n], y);
        }
        float zv = b2f(zbuf[gt * D_INNER + d]);
        float sz = zv / (1.f + __expf(-zv));
        yf[gt * D_INNER + d] = f2b((y + u * Dv) * sz);
    }
}

// ---------------------------------------------------------------- launch
extern "C" void kernel_launch(void* const* d_in, const int* in_sizes, int n_in,
                              void* d_out, int out_size, void* d_ws, size_t ws_size,
                              hipStream_t stream) {
    const float* x      = (const float*)d_in[0];
    const float* ln_g   = (const float*)d_in[1];
    const float* ln_b   = (const float*)d_in[2];
    const float* W_in   = (const float*)d_in[3];
    const float* conv_w = (const float*)d_in[4];
    const float* conv_b = (const float*)d_in[5];
    const float* A_log  = (const float*)d_in[6];
    const float* D_par  = (const float*)d_in[7];
    const float* xpw    = (const float*)d_in[8];
    const float* dtw    = (const float*)d_in[9];
    const float* dtb    = (const float*)d_in[10];
    const float* W_out  = (const float*)d_in[11];
    float* out = (float*)d_out;

    char* ws = (char*)d_ws;
    // workspace (79,953,920 B), stage-lifetime aliased:
    //  [0,        8388608)  xn bf16 -> chs/sst bf16 (scan) -> wOutb bf16 (after scan_final)
    //  [8388608, 41943040)  xc fp32 -> delta fp32 -> P0 fp32 @8388608 + P1 fp32 @25165824
    //  [41943040,58720256)  z bf16  <- yf aliases z
    //  [58720256,75497472)  wInb bf16 -> xcs bf16
    //  [75497472,77594624)  xdbl fp32 (4096x128)
    //  [77594624,78643200)  sumdl; [78643200..] drb, dtwb, xpwb
    bf16*  xn    = (bf16*)(ws + 0);
    bf16*  chs   = (bf16*)(ws + 0);
    bf16*  sst   = chs;
    short* wOutb = (short*)(ws + 0);           // after scan kernels are done
    float* xc    = (float*)(ws + 8388608);
    float* delta = xc;
    float* P0    = (float*)(ws + 8388608);     // after delta is dead (post scan_final)
    bf16*  z     = (bf16*)(ws + 41943040);
    bf16*  yf    = z;
    short* wInb  = (short*)(ws + 58720256);
    bf16*  xcs   = (bf16*)(ws + 58720256);
    float* xdbl  = (float*)(ws + 75497472);
    float* sumdl = (float*)(ws + 77594624);
    short* drb   = (short*)(ws + 78643200);
    short* dtwb  = (short*)(ws + 79167488);
    short* xpwb  = (short*)(ws + 79429632);

    // fused prep: LN + f2b(W_in) + prep(xpw) + f2b(dtw) + zero(xdbl)
    k_prep<<<9088, 256, 0, stream>>>(x, ln_g, ln_b, xn, W_in, wInb, xpw, xpwb, dtw, dtwb, xdbl);
    // in-proj GEMM: 4096 x 4096 x 1024, NT=128 -> 1024 blocks (128x128 tile, 16 MFMA/wave/K-step)
    k_gemm_mfma<128><<<dim3(4096 / 128, 32, 1), 256, 0, stream>>>(
        (const short*)xn, wInb, 2 * D_INNER, D_MODEL, 0, xc, z, nullptr, nullptr, nullptr);
    k_conv<<<(NTOK * D_INNER) / 256, 256, 0, stream>>>(xc, conv_w, conv_b, xcs);
    // xproj GEMM: 4096 x 128 x 2048, NT=64, split-K=8 atomic -> 512 blocks
    k_gemm_mfma<64><<<dim3(2, 32, 8), 256, 0, stream>>>(
        (const short*)xcs, xpwb, XDS, D_INNER, 2, xdbl, nullptr, nullptr, nullptr, nullptr);
    // delta GEMM: 4096 x 2048 x 64, NT=64 -> 1024 blocks, softplus epilogue
    k_extract_dr<<<(NTOK * DTRANK / 4) / 256, 256, 0, stream>>>(xdbl, drb);
    k_gemm_mfma<64><<<dim3(D_INNER / 64, 32, 1), 256, 0, stream>>>(
        drb, dtwb, D_INNER, DTRANK, 3, delta, nullptr, nullptr, nullptr, dtb);
    // selective scan (3-pass, register-state formulation)
    k_scan_partialB<<<dim3(D_INNER / 256, NCH, BSZ), 256, 0, stream>>>(
        delta, xcs, xdbl, A_log, chs, sumdl);
    k_scan_combineB<<<(NPAIR * DSTATE) / 256, 256, 0, stream>>>(chs, sumdl, A_log, sst);
    k_scan_finalB<<<dim3(D_INNER / 256, NCH, BSZ), 256, 0, stream>>>(
        delta, xcs, xdbl, z, A_log, D_par, sst, yf);
    // out-proj GEMM: 4096 x 1024 x 2048, NT=128, split-K=2 -> 512 blocks + reduce
    k_f2b<<<(D_MODEL * D_INNER / 4) / 256, 256, 0, stream>>>(W_out, wOutb);
    k_gemm_mfma<128><<<dim3(D_MODEL / 128, 32, 2), 256, 0, stream>>>(
        (const short*)yf, wOutb, D_MODEL, D_INNER, 4, P0, nullptr, nullptr, nullptr, nullptr);
    k_reduce_out<<<(NTOK * D_MODEL / 4) / 256, 256, 0, stream>>>(x, P0, out);
}

// Round 2
// 373.941 us; speedup vs baseline: 1.1571x; 1.1571x over previous
//
#include <hip/hip_runtime.h>
#include <hip/hip_bf16.h>
#include <math.h>

typedef __hip_bfloat16 bf16;

#define D_MODEL 1024
#define D_INNER 2048
#define NTOK    4096   // B*L
#define SEQ     2048
#define BSZ     2
#define DSTATE  16
#define DTRANK  64
#define NCH     64
#define CHLEN   32     // SEQ / NCH
#define NPAIR   4096   // BSZ * D_INNER
#define XDS     128    // xdbl row stride (fp32), padded from 96

__device__ __forceinline__ float b2f(bf16 v) { return __bfloat162float(v); }
__device__ __forceinline__ bf16  f2b(float v) { return __float2bfloat16(v); }
__device__ __forceinline__ short f2bs(float v) {
    bf16 h = __float2bfloat16(v);
    short s; __builtin_memcpy(&s, &h, 2); return s;
}

typedef __attribute__((ext_vector_type(8))) short short8;
typedef __attribute__((ext_vector_type(4))) float f32x4;

__device__ __forceinline__ void async_copy16(const void* g, void* l) {
    __builtin_amdgcn_global_load_lds(
        (const __attribute__((address_space(1))) unsigned int*)g,
        (__attribute__((address_space(3))) unsigned int*)l,
        16, 0, 0);
}

// ---------------------------------------------------------------- fused prep
// blocks [0,4096): LayerNorm; [4096,8192): f2b W_in; [8192,8448): prep xpw;
// [8448,8576): f2b dtw; [8576,9088): zero xdbl. Uniform branch per block.
__global__ void k_prep(const float* __restrict__ x, const float* __restrict__ g,
                       const float* __restrict__ b, bf16* __restrict__ xn,
                       const float* __restrict__ W_in, short* __restrict__ wInb,
                       const float* __restrict__ xpw, short* __restrict__ xpwb,
                       const float* __restrict__ dtw, short* __restrict__ dtwb,
                       float* __restrict__ xdbl) {
    int bid = blockIdx.x;
    int tid = threadIdx.x;
    if (bid < 4096) {                       // ---- LayerNorm, one block per token
        int t = bid;
        const float* row = x + (size_t)t * D_MODEL;
        float v[4];
        float s = 0.f, q = 0.f;
#pragma unroll
        for (int i = 0; i < 4; ++i) {
            int idx = tid + i * 256;
            v[i] = row[idx];
            s += v[i]; q += v[i] * v[i];
        }
        __shared__ float sh_s[256], sh_q[256];
        sh_s[tid] = s; sh_q[tid] = q;
        __syncthreads();
        for (int o = 128; o > 0; o >>= 1) {
            if (tid < o) { sh_s[tid] += sh_s[tid + o]; sh_q[tid] += sh_q[tid + o]; }
            __syncthreads();
        }
        float mu  = sh_s[0] * (1.f / D_MODEL);
        float var = sh_q[0] * (1.f / D_MODEL) - mu * mu;
        float rs  = rsqrtf(var + 1e-5f);
#pragma unroll
        for (int i = 0; i < 4; ++i) {
            int idx = tid + i * 256;
            float o = (v[i] - mu) * rs * g[idx] + b[idx];
            xn[(size_t)t * D_MODEL + idx] = f2b(o);
        }
    } else if (bid < 8192) {                // ---- f2b W_in (float4 per thread)
        int i = (bid - 4096) * 256 + tid;
        float4 v = reinterpret_cast<const float4*>(W_in)[i];
        short4 o;
        o.x = f2bs(v.x); o.y = f2bs(v.y); o.z = f2bs(v.z); o.w = f2bs(v.w);
        reinterpret_cast<short4*>(wInb)[i] = o;
    } else if (bid < 8448) {                // ---- xpw 96x2048 -> padded 128x2048 bf16
        int i = (bid - 8192) * 256 + tid;
        int row = i >> 9;
        short4 o;
        if (row < 96) {
            float4 v = reinterpret_cast<const float4*>(xpw)[i];
            o.x = f2bs(v.x); o.y = f2bs(v.y); o.z = f2bs(v.z); o.w = f2bs(v.w);
        } else { o.x = o.y = o.z = o.w = 0; }
        reinterpret_cast<short4*>(xpwb)[i] = o;
    } else if (bid < 8576) {                // ---- f2b dtw
        int i = (bid - 8448) * 256 + tid;
        float4 v = reinterpret_cast<const float4*>(dtw)[i];
        short4 o;
        o.x = f2bs(v.x); o.y = f2bs(v.y); o.z = f2bs(v.z); o.w = f2bs(v.w);
        reinterpret_cast<short4*>(dtwb)[i] = o;
    } else {                                // ---- zero xdbl
        int i = (bid - 8576) * 256 + tid;
        reinterpret_cast<float4*>(xdbl)[i] = (float4){0.f, 0.f, 0.f, 0.f};
    }
}

// ---------------------------------------------------------------- fp32 -> bf16 convert
__global__ void k_f2b(const float* __restrict__ in, short* __restrict__ out) {
    int i = blockIdx.x * 256 + threadIdx.x;
    float4 v = reinterpret_cast<const float4*>(in)[i];
    short4 o;
    o.x = f2bs(v.x); o.y = f2bs(v.y); o.z = f2bs(v.z); o.w = f2bs(v.w);
    reinterpret_cast<short4*>(out)[i] = o;
}

// --------------------------------------------- dr = xdbl[:, 0:64] -> bf16 (4096x64)
__global__ void k_extract_dr(const float* __restrict__ xdbl, short* __restrict__ drb) {
    int i = blockIdx.x * 256 + threadIdx.x;
    int t = i >> 4;
    int jg = (i & 15) * 4;
    float4 v = *reinterpret_cast<const float4*>(&xdbl[(size_t)t * XDS + jg]);
    short4 o;
    o.x = f2bs(v.x); o.y = f2bs(v.y); o.z = f2bs(v.z); o.w = f2bs(v.w);
    *reinterpret_cast<short4*>(&drb[(size_t)t * DTRANK + jg]) = o;
}

// ---------------------------------------------------------------- MFMA GEMM (NT=64)
// m97-style 128 x 64 block tile, BK=32, double-buffered single-barrier K-loop.
// Used for the skinny GEMMs (xproj N=128, delta K=64).
// mode 2: atomicAdd(Cf, acc)                      (xproj, split-K via blockIdx.z)
// mode 3: Cf = softplus(acc + bias[col]) fp32     (delta)
#define GBK 32
template<int NT>
__global__ __launch_bounds__(256) void k_gemm_mfma(
    const short* __restrict__ A, const short* __restrict__ Bw,
    int N, int K, int mode,
    float* __restrict__ Cf, bf16* __restrict__ Cz,
    const float* __restrict__ res, float* __restrict__ Cout,
    const float* __restrict__ bias)
{
    constexpr int ABUF = 128 * GBK;            // shorts per A buffer (8 KB)
    constexpr int BBUF = NT * GBK;             // shorts per B buffer
    constexpr int AF   = (NT == 128) ? 4 : 2;  // row frags per wave
    __shared__ short As[2 * ABUF];
    __shared__ short Bs[2 * BBUF];
    const int tid  = threadIdx.x;
    const int lane = tid & 63;
    const int wave = tid >> 6;
    const int rowbase = (NT == 128) ? (wave >> 1) * 64 : wave * 32;
    const int colbase = (NT == 128) ? (wave & 1) * 64 : 0;
    const int m0 = blockIdx.y * 128;
    const int n0 = blockIdx.x * NT;
    const int lm = lane & 15;
    const int koff = (((lane >> 4) ^ ((lane >> 1) & 3)) * 8);

    const int srow = tid >> 2;                              // 0..63
    const int skc  = (((tid & 3) ^ ((tid >> 3) & 3)) * 8);  // swizzled source chunk
    const size_t a_off0 = (size_t)(m0 + srow) * K + skc;
    const size_t a_off1 = (size_t)(m0 + srow + 64) * K + skc;
    const size_t b_off0 = (size_t)(n0 + srow) * K + skc;
    size_t b_off1 = 0;
    if constexpr (NT == 128) b_off1 = (size_t)(n0 + srow + 64) * K + skc;

    f32x4 acc[AF][4];
#pragma unroll
    for (int i = 0; i < AF; ++i)
#pragma unroll
        for (int j = 0; j < 4; ++j)
            acc[i][j] = (f32x4){0.f, 0.f, 0.f, 0.f};

    const int kchunk = K / gridDim.z;
    const int kbeg = blockIdx.z * kchunk;
    const int kend = kbeg + kchunk;

    // prologue: tile 0 into buffer 0
    {
        char* aD = (char*)As + tid * 16;
        char* bD = (char*)Bs + tid * 16;
        async_copy16(A + a_off0 + kbeg, aD);
        async_copy16(A + a_off1 + kbeg, aD + 4096);
        async_copy16(Bw + b_off0 + kbeg, bD);
        if constexpr (NT == 128) async_copy16(Bw + b_off1 + kbeg, bD + 4096);
    }

    int cur = 0;
    for (int k0 = kbeg; k0 < kend; k0 += GBK) {
        __syncthreads();   // buf[cur] ready; compute on buf[cur^1] done
        int k1 = k0 + GBK;
        if (k1 < kend) {
            int nxt = cur ^ 1;
            char* aD = (char*)As + nxt * (ABUF * 2) + tid * 16;
            char* bD = (char*)Bs + nxt * (BBUF * 2) + tid * 16;
            async_copy16(A + a_off0 + k1, aD);
            async_copy16(A + a_off1 + k1, aD + 4096);
            async_copy16(Bw + b_off0 + k1, bD);
            if constexpr (NT == 128) async_copy16(Bw + b_off1 + k1, bD + 4096);
        }

        const short* Ab = As + cur * ABUF;
        const short* Bb = Bs + cur * BBUF;
        short8 af[AF], bf[4];
#pragma unroll
        for (int t = 0; t < AF; ++t)
            af[t] = *reinterpret_cast<const short8*>(&Ab[(rowbase + t * 16 + lm) * GBK + koff]);
#pragma unroll
        for (int t = 0; t < 4; ++t)
            bf[t] = *reinterpret_cast<const short8*>(&Bb[(colbase + t * 16 + lm) * GBK + koff]);
#pragma unroll
        for (int tm = 0; tm < AF; ++tm)
#pragma unroll
            for (int tn = 0; tn < 4; ++tn)
                acc[tm][tn] = __builtin_amdgcn_mfma_f32_16x16x32_bf16(
                    af[tm], bf[tn], acc[tm][tn], 0, 0, 0);
        cur ^= 1;
    }

    const int rq = (lane >> 4) * 4;
#pragma unroll
    for (int tm = 0; tm < AF; ++tm) {
#pragma unroll
        for (int tn = 0; tn < 4; ++tn) {
            f32x4 v = acc[tm][tn];
            int col = n0 + colbase + tn * 16 + lm;
#pragma unroll
            for (int r = 0; r < 4; ++r) {
                int row = m0 + rowbase + tm * 16 + rq + r;
                float val = v[r];
                if (mode == 0) {
                    if (col < D_INNER) Cf[(size_t)row * D_INNER + col] = val;
                    else               Cz[(size_t)row * D_INNER + (col - D_INNER)] = f2b(val);
                } else if (mode == 1) {
                    Cout[(size_t)row * N + col] = val + res[(size_t)row * N + col];
                } else if (mode == 2) {
                    atomicAdd(&Cf[(size_t)row * N + col], val);
                } else if (mode == 3) {
                    float a = val + bias[col];
                    float sp = (a > 20.f) ? a : log1pf(expf(a));
                    Cf[(size_t)row * N + col] = sp;
                } else {
                    Cf[(size_t)blockIdx.z * 4096 * N + (size_t)row * N + col] = val;
                }
            }
        }
    }
}

// ---------------------------------------------------------------- 8-phase 256x256 GEMM
// T2+T3+T4+T5 schedule (plain-HIP port of the 256^2 8-phase template).
// 512 threads = 8 waves (2M x 4N); wave output 128x64; BK=64; 2 LDS buffers,
// staging runs ~1.5 K-tiles ahead at half-tile granularity; vmcnt(4) once per
// K-tile (never 0 in steady state). LDS XOR-swizzle (16B chunk ^= row&7) with
// the inverse swizzle pre-applied to the per-lane GLOBAL source (both-sides rule).
// Per K-tile: 4 phases = C-quadrants (0,0),(0,1),(1,1),(1,0); 16 MFMA each.
// mode 0: split at D_INNER -> Cf fp32 / Cz bf16   (in-proj)
// mode 4: Cf[z*4096*N + row*N + col] = acc        (split-K partials, out-proj)
__global__ __launch_bounds__(512, 2) void k_gemm8(
    const short* __restrict__ A, const short* __restrict__ Bw,
    int N, int K, int mode,
    float* __restrict__ Cf, bf16* __restrict__ Cz)
{
    __shared__ short lds[65536];   // A: shorts [0,32768) = 2 buf x 256x64; B: [32768,65536)
    char* ldsc = (char*)lds;
    const int tid  = threadIdx.x;
    const int lane = tid & 63;
    const int wave = tid >> 6;     // 0..7
    const int wr   = wave >> 2;    // 0..1  (128-row half of the 256-row tile)
    const int wc   = wave & 3;     // 0..3  (64-col slice of the 256-col tile)
    const int lm   = lane & 15;
    const int q4   = lane >> 4;
    const int m0 = blockIdx.y * 256;
    const int n0 = blockIdx.x * 256;

    // staging geometry: thread covers LDS bytes tid*16 (+8192) of a 16 KB half-tile
    const int r0  = tid >> 3;                        // LDS row 0..63 (and +64)
    const int ksw = ((tid & 7) ^ (r0 & 7)) << 3;     // inverse-swizzled source chunk (shorts)

    const int NTt   = K / 64 / gridDim.z;            // K-tiles in this split-K chunk
    const int kbase = blockIdx.z * NTt;

    const short* gA = A  + (size_t)(m0 + r0) * K + ksw;
    const short* gB = Bw + (size_t)(n0 + r0) * K + ksw;

#define STAGE_A8(h, kt, bb) do {                                             \
        const short* s_ = gA + (size_t)(h) * 128 * K + (size_t)(kt) * 64;    \
        char* d_ = ldsc + (bb) * 32768 + (h) * 16384 + tid * 16;             \
        async_copy16(s_, d_);                                                \
        async_copy16(s_ + (size_t)64 * K, d_ + 8192);                        \
    } while (0)
#define STAGE_B8(h, kt, bb) do {                                             \
        const short* s_ = gB + (size_t)(h) * 128 * K + (size_t)(kt) * 64;    \
        char* d_ = ldsc + 65536 + (bb) * 32768 + (h) * 16384 + tid * 16;     \
        async_copy16(s_, d_);                                                \
        async_copy16(s_ + (size_t)64 * K, d_ + 8192);                        \
    } while (0)

    f32x4 acc[2][2][4][2];
#pragma unroll
    for (int a = 0; a < 2; ++a)
#pragma unroll
        for (int c = 0; c < 2; ++c)
#pragma unroll
            for (int t = 0; t < 4; ++t)
#pragma unroll
                for (int u = 0; u < 2; ++u)
                    acc[a][c][t][u] = (f32x4){0.f, 0.f, 0.f, 0.f};

    // prologue: B(0), A(0) -> buf0; B(1) -> buf1. Wait tile 0 (leave B(1) in flight).
    STAGE_B8(0, kbase + 0, 0); STAGE_B8(1, kbase + 0, 0);
    STAGE_A8(0, kbase + 0, 0); STAGE_A8(1, kbase + 0, 0);
    STAGE_B8(0, kbase + 1, 1); STAGE_B8(1, kbase + 1, 1);
    asm volatile("s_waitcnt vmcnt(4)" ::: "memory");
    __builtin_amdgcn_s_barrier();

    short8 af[4][2], bf0[2][2], bf1[2][2];

    for (int tt = 0; tt < NTt; ++tt) {
        const int b  = tt & 1;
        const int bn = b ^ 1;
        const short* lA = lds + b * 16384 + wr * 8192;               // this wave's A half
        const short* lB = lds + 32768 + b * 16384 + (wc >> 1) * 8192; // this wave's B half
        const bool stA = (tt + 1 < NTt);
        const bool stB = (tt + 2 < NTt);

        // ---------------- P0: ld af(qr=0) [8] + bf0(qc=0) [4]; stage A-half0(tt+1)
#pragma unroll
        for (int t = 0; t < 4; ++t) {
            const int rr = t * 16 + lm;
            const int x8 = rr & 7;
            af[t][0] = *reinterpret_cast<const short8*>(&lA[rr * 64 + ((q4 ^ x8) << 3)]);
            af[t][1] = *reinterpret_cast<const short8*>(&lA[rr * 64 + (((4 + q4) ^ x8) << 3)]);
        }
#pragma unroll
        for (int t = 0; t < 2; ++t) {
            const int rr = (wc & 1) * 64 + t * 16 + lm;
            const int x8 = rr & 7;
            bf0[t][0] = *reinterpret_cast<const short8*>(&lB[rr * 64 + ((q4 ^ x8) << 3)]);
            bf0[t][1] = *reinterpret_cast<const short8*>(&lB[rr * 64 + (((4 + q4) ^ x8) << 3)]);
        }
        if (stA) STAGE_A8(0, kbase + tt + 1, bn);
        __builtin_amdgcn_s_barrier();
        asm volatile("s_waitcnt lgkmcnt(0)" ::: "memory");
        __builtin_amdgcn_s_setprio(1);
#pragma unroll
        for (int t = 0; t < 4; ++t)
#pragma unroll
            for (int u = 0; u < 2; ++u) {
                acc[0][0][t][u] = __builtin_amdgcn_mfma_f32_16x16x32_bf16(af[t][0], bf0[u][0], acc[0][0][t][u], 0, 0, 0);
                acc[0][0][t][u] = __builtin_amdgcn_mfma_f32_16x16x32_bf16(af[t][1], bf0[u][1], acc[0][0][t][u], 0, 0, 0);
            }
        __builtin_amdgcn_s_setprio(0);
        __builtin_amdgcn_s_barrier();

        // ---------------- P1: ld bf1(qc=1) [4]; stage A-half1(tt+1); compute (0,1)
#pragma unroll
        for (int t = 0; t < 2; ++t) {
            const int rr = (wc & 1) * 64 + 32 + t * 16 + lm;
            const int x8 = rr & 7;
            bf1[t][0] = *reinterpret_cast<const short8*>(&lB[rr * 64 + ((q4 ^ x8) << 3)]);
            bf1[t][1] = *reinterpret_cast<const short8*>(&lB[rr * 64 + (((4 + q4) ^ x8) << 3)]);
        }
        if (stA) STAGE_A8(1, kbase + tt + 1, bn);
        __builtin_amdgcn_s_barrier();
        asm volatile("s_waitcnt lgkmcnt(0)" ::: "memory");
        __builtin_amdgcn_s_setprio(1);
#pragma unroll
        for (int t = 0; t < 4; ++t)
#pragma unroll
            for (int u = 0; u < 2; ++u) {
                acc[0][1][t][u] = __builtin_amdgcn_mfma_f32_16x16x32_bf16(af[t][0], bf1[u][0], acc[0][1][t][u], 0, 0, 0);
                acc[0][1][t][u] = __builtin_amdgcn_mfma_f32_16x16x32_bf16(af[t][1], bf1[u][1], acc[0][1][t][u], 0, 0, 0);
            }
        __builtin_amdgcn_s_setprio(0);
        __builtin_amdgcn_s_barrier();

        // ---------------- P2: ld af(qr=1) [8]; stage B-half0(tt+2); compute (1,1)
#pragma unroll
        for (int t = 0; t < 4; ++t) {
            const int rr = 64 + t * 16 + lm;
            const int x8 = rr & 7;
            af[t][0] = *reinterpret_cast<const short8*>(&lA[rr * 64 + ((q4 ^ x8) << 3)]);
            af[t][1] = *reinterpret_cast<const short8*>(&lA[rr * 64 + (((4 + q4) ^ x8) << 3)]);
        }
        if (stB) STAGE_B8(0, kbase + tt + 2, b);
        __builtin_amdgcn_s_barrier();
        asm volatile("s_waitcnt lgkmcnt(0)" ::: "memory");
        __builtin_amdgcn_s_setprio(1);
#pragma unroll
        for (int t = 0; t < 4; ++t)
#pragma unroll
            for (int u = 0; u < 2; ++u) {
                acc[1][1][t][u] = __builtin_amdgcn_mfma_f32_16x16x32_bf16(af[t][0], bf1[u][0], acc[1][1][t][u], 0, 0, 0);
                acc[1][1][t][u] = __builtin_amdgcn_mfma_f32_16x16x32_bf16(af[t][1], bf1[u][1], acc[1][1][t][u], 0, 0, 0);
            }
        __builtin_amdgcn_s_setprio(0);
        __builtin_amdgcn_s_barrier();

        // ---------------- P3: stage B-half1(tt+2); vmcnt; compute (1,0) with bf0
        if (stB) {
            STAGE_B8(1, kbase + tt + 2, b);
            asm volatile("s_waitcnt vmcnt(4)" ::: "memory");   // tile tt+1 fully landed
        } else if (stA) {
            asm volatile("s_waitcnt vmcnt(0)" ::: "memory");   // drain A(NTt-1)
        }
        __builtin_amdgcn_s_barrier();
        __builtin_amdgcn_s_setprio(1);
#pragma unroll
        for (int t = 0; t < 4; ++t)
#pragma unroll
            for (int u = 0; u < 2; ++u) {
                acc[1][0][t][u] = __builtin_amdgcn_mfma_f32_16x16x32_bf16(af[t][0], bf0[u][0], acc[1][0][t][u], 0, 0, 0);
                acc[1][0][t][u] = __builtin_amdgcn_mfma_f32_16x16x32_bf16(af[t][1], bf0[u][1], acc[1][0][t][u], 0, 0, 0);
            }
        __builtin_amdgcn_s_setprio(0);
        __builtin_amdgcn_s_barrier();
    }
#undef STAGE_A8
#undef STAGE_B8

    // -------- epilogue
    const int rq = (lane >> 4) * 4;
#pragma unroll
    for (int qr = 0; qr < 2; ++qr)
#pragma unroll
    for (int qc = 0; qc < 2; ++qc)
#pragma unroll
    for (int t = 0; t < 4; ++t)
#pragma unroll
    for (int u = 0; u < 2; ++u) {
        f32x4 v = acc[qr][qc][t][u];
        const int col = n0 + wc * 64 + qc * 32 + u * 16 + lm;
#pragma unroll
        for (int r = 0; r < 4; ++r) {
            const int row = m0 + wr * 128 + qr * 64 + t * 16 + rq + r;
            if (mode == 0) {
                if (col < D_INNER) Cf[(size_t)row * D_INNER + col] = v[r];
                else               Cz[(size_t)row * D_INNER + (col - D_INNER)] = f2b(v[r]);
            } else {
                Cf[(size_t)blockIdx.z * 4096 * N + (size_t)row * N + col] = v[r];
            }
        }
    }
}

// ------------------------------------------------- out = x + P0 + P1 (out-proj reduce)
__global__ void k_reduce_out(const float* __restrict__ x, const float* __restrict__ P,
                             float* __restrict__ out) {
    int i = blockIdx.x * 256 + threadIdx.x;
    float4 a = reinterpret_cast<const float4*>(x)[i];
    float4 p = reinterpret_cast<const float4*>(P)[i];
    float4 q = reinterpret_cast<const float4*>(P + (size_t)4096 * 1024)[i];
    float4 o;
    o.x = a.x + p.x + q.x; o.y = a.y + p.y + q.y;
    o.z = a.z + p.z + q.z; o.w = a.w + p.w + q.w;
    reinterpret_cast<float4*>(out)[i] = o;
}

// ------------------------------------------------- causal depthwise conv + SiLU
__global__ void k_conv(const float* __restrict__ xc, const float* __restrict__ cw,
                       const float* __restrict__ cb, bf16* __restrict__ xcs) {
    size_t idx = (size_t)blockIdx.x * blockDim.x + threadIdx.x;
    int d = (int)(idx & (D_INNER - 1));
    int l = (int)((idx >> 11) & (SEQ - 1));
    float w0 = cw[d * 4 + 0], w1 = cw[d * 4 + 1];
    float w2 = cw[d * 4 + 2], w3 = cw[d * 4 + 3];
    const float* base = xc + idx;
    float acc = cb[d] + w3 * base[0];
    if (l >= 1) acc += w2 * base[-(int)D_INNER];
    if (l >= 2) acc += w1 * base[-2 * (int)D_INNER];
    if (l >= 3) acc += w0 * base[-3 * (int)D_INNER];
    xcs[idx] = f2b(acc / (1.f + __expf(-acc)));   // silu
}

// ------------------------------------------------- scan pass A: per-chunk partials
__global__ __launch_bounds__(256) void k_scan_partialB(
    const float* __restrict__ delta, const bf16* __restrict__ xcs,
    const float* __restrict__ xdbl, const float* __restrict__ A_log,
    bf16* __restrict__ chs, float* __restrict__ sumdl)
{
    __shared__ float Bsh[CHLEN][16];
    const int tid = threadIdx.x;
    const int d = blockIdx.x * 256 + tid;
    const int chunk = blockIdx.y;
    const int b = blockIdx.z;
    const size_t tbase = (size_t)b * SEQ + (size_t)chunk * CHLEN;

    if (tid < 128) {
        int t = tid >> 2, j = (tid & 3) * 4;
        float4 v = *reinterpret_cast<const float4*>(&xdbl[(tbase + t) * XDS + 64 + j]);
        *reinterpret_cast<float4*>(&Bsh[t][j]) = v;
    }
    float An[16];
#pragma unroll
    for (int j = 0; j < 4; ++j) {
        float4 v = *reinterpret_cast<const float4*>(&A_log[(size_t)d * DSTATE + j * 4]);
        An[j * 4 + 0] = -__expf(v.x); An[j * 4 + 1] = -__expf(v.y);
        An[j * 4 + 2] = -__expf(v.z); An[j * 4 + 3] = -__expf(v.w);
    }
    __syncthreads();

    float s[16];
#pragma unroll
    for (int n = 0; n < 16; ++n) s[n] = 0.f;
    float sd = 0.f;
    for (int t = 0; t < CHLEN; ++t) {
        size_t gt = tbase + t;
        float dl = delta[gt * D_INNER + d];
        float u  = b2f(xcs[gt * D_INNER + d]);
        float dlu = dl * u;
        sd += dl;
#pragma unroll
        for (int n = 0; n < 16; ++n) {
            float dA = __expf(dl * An[n]);
            s[n] = fmaf(dA, s[n], dlu * Bsh[t][n]);
        }
    }
    const int pair = b * D_INNER + d;
    bf16* co = chs + ((size_t)pair * NCH + chunk) * DSTATE;
#pragma unroll
    for (int n = 0; n < 16; ++n) co[n] = f2b(s[n]);
    sumdl[(size_t)pair * NCH + chunk] = sd;
}

// ------------------------------------------------- scan pass B: chunk-prefix combine
// sst ALIASES chs: read chunk-sum before writing entry state (same thread+element).
__global__ void k_scan_combineB(const bf16* __restrict__ chs, const float* __restrict__ sumdl,
                                const float* __restrict__ A_log, bf16* __restrict__ sst) {
    int idx = blockIdx.x * 256 + threadIdx.x;
    int pair = idx >> 4;
    int n = idx & 15;
    int d = pair & (D_INNER - 1);
    float An = -__expf(A_log[(size_t)d * DSTATE + n]);
    float s = 0.f;
    for (int c = 0; c < NCH; ++c) {
        size_t o = ((size_t)pair * NCH + c) * DSTATE + n;
        float loc = b2f(chs[o]);
        float ap = __expf(An * sumdl[(size_t)pair * NCH + c]);
        sst[o] = f2b(s);
        s = fmaf(ap, s, loc);
    }
}

// ------------------------------------------------- scan pass C: final y + gate
// yf aliases zbuf elementwise (same-thread read-then-write).
__global__ __launch_bounds__(256) void k_scan_finalB(
    const float* __restrict__ delta, const bf16* __restrict__ xcs,
    const float* __restrict__ xdbl, const bf16* __restrict__ zbuf,
    const float* __restrict__ A_log, const float* __restrict__ Dp,
    const bf16* __restrict__ sst, bf16* __restrict__ yf)
{
    __shared__ float BC[CHLEN][32];   // [t][0:16]=B, [t][16:32]=C
    const int tid = threadIdx.x;
    const int d = blockIdx.x * 256 + tid;
    const int chunk = blockIdx.y;
    const int b = blockIdx.z;
    const size_t tbase = (size_t)b * SEQ + (size_t)chunk * CHLEN;

    {
        int t = tid >> 3, j = (tid & 7) * 4;
        float4 v = *reinterpret_cast<const float4*>(&xdbl[(tbase + t) * XDS + 64 + j]);
        *reinterpret_cast<float4*>(&BC[t][j]) = v;
    }
    float An[16];
#pragma unroll
    for (int j = 0; j < 4; ++j) {
        float4 v = *reinterpret_cast<const float4*>(&A_log[(size_t)d * DSTATE + j * 4]);
        An[j * 4 + 0] = -__expf(v.x); An[j * 4 + 1] = -__expf(v.y);
        An[j * 4 + 2] = -__expf(v.z); An[j * 4 + 3] = -__expf(v.w);
    }
    const int pair = b * D_INNER + d;
    float s[16];
    const bf16* so = sst + ((size_t)pair * NCH + chunk) * DSTATE;
#pragma unroll
    for (int n = 0; n < 16; ++n) s[n] = b2f(so[n]);
    const float Dv = Dp[d];
    __syncthreads();

    for (int t = 0; t < CHLEN; ++t) {
        size_t gt = tbase + t;
        float dl = delta[gt * D_INNER + d];
        float u  = b2f(xcs[gt * D_INNER + d]);
        float dlu = dl * u;
        float y = 0.f;
#pragma unroll
        for (int n = 0; n < 16; ++n) {
            float dA = __expf(dl * An[n]);
            s[n] = fmaf(dA, s[n], dlu * BC[t][n]);
            y = fmaf(s[n], BC[t][16 + n], y);
        }
        float zv = b2f(zbuf[gt * D_INNER + d]);
        float sz = zv / (1.f + __expf(-zv));
        yf[gt * D_INNER + d] = f2b((y + u * Dv) * sz);
    }
}

// ---------------------------------------------------------------- launch
extern "C" void kernel_launch(void* const* d_in, const int* in_sizes, int n_in,
                              void* d_out, int out_size, void* d_ws, size_t ws_size,
                              hipStream_t stream) {
    const float* x      = (const float*)d_in[0];
    const float* ln_g   = (const float*)d_in[1];
    const float* ln_b   = (const float*)d_in[2];
    const float* W_in   = (const float*)d_in[3];
    const float* conv_w = (const float*)d_in[4];
    const float* conv_b = (const float*)d_in[5];
    const float* A_log  = (const float*)d_in[6];
    const float* D_par  = (const float*)d_in[7];
    const float* xpw    = (const float*)d_in[8];
    const float* dtw    = (const float*)d_in[9];
    const float* dtb    = (const float*)d_in[10];
    const float* W_out  = (const float*)d_in[11];
    float* out = (float*)d_out;

    char* ws = (char*)d_ws;
    // workspace (79,953,920 B), stage-lifetime aliased:
    //  [0,        8388608)  xn bf16 -> chs/sst bf16 (scan) -> wOutb bf16 (after scan_final)
    //  [8388608, 41943040)  xc fp32 -> delta fp32 -> P0 fp32 @8388608 + P1 fp32 @25165824
    //  [41943040,58720256)  z bf16  <- yf aliases z
    //  [58720256,75497472)  wInb bf16 -> xcs bf16
    //  [75497472,77594624)  xdbl fp32 (4096x128)
    //  [77594624,78643200)  sumdl; [78643200..] drb, dtwb, xpwb
    bf16*  xn    = (bf16*)(ws + 0);
    bf16*  chs   = (bf16*)(ws + 0);
    bf16*  sst   = chs;
    short* wOutb = (short*)(ws + 0);           // after scan kernels are done
    float* xc    = (float*)(ws + 8388608);
    float* delta = xc;
    float* P0    = (float*)(ws + 8388608);     // after delta is dead (post scan_final)
    bf16*  z     = (bf16*)(ws + 41943040);
    bf16*  yf    = z;
    short* wInb  = (short*)(ws + 58720256);
    bf16*  xcs   = (bf16*)(ws + 58720256);
    float* xdbl  = (float*)(ws + 75497472);
    float* sumdl = (float*)(ws + 77594624);
    short* drb   = (short*)(ws + 78643200);
    short* dtwb  = (short*)(ws + 79167488);
    short* xpwb  = (short*)(ws + 79429632);

    // fused prep: LN + f2b(W_in) + prep(xpw) + f2b(dtw) + zero(xdbl)
    k_prep<<<9088, 256, 0, stream>>>(x, ln_g, ln_b, xn, W_in, wInb, xpw, xpwb, dtw, dtwb, xdbl);
    // in-proj GEMM: 4096 x 4096 x 1024, 8-phase 256^2 -> 256 blocks (1/CU)
    k_gemm8<<<dim3(4096 / 256, 4096 / 256, 1), 512, 0, stream>>>(
        (const short*)xn, wInb, 2 * D_INNER, D_MODEL, 0, xc, z);
    k_conv<<<(NTOK * D_INNER) / 256, 256, 0, stream>>>(xc, conv_w, conv_b, xcs);
    // xproj GEMM: 4096 x 128 x 2048, NT=64, split-K=8 atomic -> 512 blocks
    k_gemm_mfma<64><<<dim3(2, 32, 8), 256, 0, stream>>>(
        (const short*)xcs, xpwb, XDS, D_INNER, 2, xdbl, nullptr, nullptr, nullptr, nullptr);
    // delta GEMM: 4096 x 2048 x 64, NT=64 -> 1024 blocks, softplus epilogue
    k_extract_dr<<<(NTOK * DTRANK / 4) / 256, 256, 0, stream>>>(xdbl, drb);
    k_gemm_mfma<64><<<dim3(D_INNER / 64, 32, 1), 256, 0, stream>>>(
        drb, dtwb, D_INNER, DTRANK, 3, delta, nullptr, nullptr, nullptr, dtb);
    // selective scan (3-pass, register-state formulation)
    k_scan_partialB<<<dim3(D_INNER / 256, NCH, BSZ), 256, 0, stream>>>(
        delta, xcs, xdbl, A_log, chs, sumdl);
    k_scan_combineB<<<(NPAIR * DSTATE) / 256, 256, 0, stream>>>(chs, sumdl, A_log, sst);
    k_scan_finalB<<<dim3(D_INNER / 256, NCH, BSZ), 256, 0, stream>>>(
        delta, xcs, xdbl, z, A_log, D_par, sst, yf);
    // out-proj GEMM: 4096 x 1024 x 2048, 8-phase 256^2 split-K=2 -> 128 blocks + reduce
    k_f2b<<<(D_MODEL * D_INNER / 4) / 256, 256, 0, stream>>>(W_out, wOutb);
    k_gemm8<<<dim3(D_MODEL / 256, 4096 / 256, 2), 512, 0, stream>>>(
        (const short*)yf, wOutb, D_MODEL, D_INNER, 4, P0, nullptr);
    k_reduce_out<<<(NTOK * D_MODEL / 4) / 256, 256, 0, stream>>>(x, P0, out);
}

// Round 3
// 363.200 us; speedup vs baseline: 1.1913x; 1.0296x over previous
//
#include <hip/hip_runtime.h>
#include <hip/hip_bf16.h>
#include <math.h>

typedef __hip_bfloat16 bf16;

#define D_MODEL 1024
#define D_INNER 2048
#define NTOK    4096   // B*L
#define SEQ     2048
#define BSZ     2
#define DSTATE  16
#define DTRANK  64
#define NCH     64
#define CHLEN   32     // SEQ / NCH
#define NPAIR   4096   // BSZ * D_INNER
#define XDS     128    // xdbl row stride (fp32), padded from 96

__device__ __forceinline__ float b2f(bf16 v) { return __bfloat162float(v); }
__device__ __forceinline__ bf16  f2b(float v) { return __float2bfloat16(v); }
__device__ __forceinline__ short f2bs(float v) {
    bf16 h = __float2bfloat16(v);
    short s; __builtin_memcpy(&s, &h, 2); return s;
}

typedef __attribute__((ext_vector_type(8))) short short8;
typedef __attribute__((ext_vector_type(4))) float f32x4;

__device__ __forceinline__ void async_copy16(const void* g, void* l) {
    __builtin_amdgcn_global_load_lds(
        (const __attribute__((address_space(1))) unsigned int*)g,
        (__attribute__((address_space(3))) unsigned int*)l,
        16, 0, 0);
}

// ---------------------------------------------------------------- fused prep
// blocks [0,4096): LayerNorm; [4096,8192): f2b W_in; [8192,8448): prep xpw;
// [8448,8576): f2b dtw; [8576,9088): zero xdbl. Uniform branch per block.
__global__ void k_prep(const float* __restrict__ x, const float* __restrict__ g,
                       const float* __restrict__ b, bf16* __restrict__ xn,
                       const float* __restrict__ W_in, short* __restrict__ wInb,
                       const float* __restrict__ xpw, short* __restrict__ xpwb,
                       const float* __restrict__ dtw, short* __restrict__ dtwb,
                       float* __restrict__ xdbl) {
    int bid = blockIdx.x;
    int tid = threadIdx.x;
    if (bid < 4096) {                       // ---- LayerNorm, one block per token
        int t = bid;
        const float* row = x + (size_t)t * D_MODEL;
        float v[4];
        float s = 0.f, q = 0.f;
#pragma unroll
        for (int i = 0; i < 4; ++i) {
            int idx = tid + i * 256;
            v[i] = row[idx];
            s += v[i]; q += v[i] * v[i];
        }
        __shared__ float sh_s[256], sh_q[256];
        sh_s[tid] = s; sh_q[tid] = q;
        __syncthreads();
        for (int o = 128; o > 0; o >>= 1) {
            if (tid < o) { sh_s[tid] += sh_s[tid + o]; sh_q[tid] += sh_q[tid + o]; }
            __syncthreads();
        }
        float mu  = sh_s[0] * (1.f / D_MODEL);
        float var = sh_q[0] * (1.f / D_MODEL) - mu * mu;
        float rs  = rsqrtf(var + 1e-5f);
#pragma unroll
        for (int i = 0; i < 4; ++i) {
            int idx = tid + i * 256;
            float o = (v[i] - mu) * rs * g[idx] + b[idx];
            xn[(size_t)t * D_MODEL + idx] = f2b(o);
        }
    } else if (bid < 8192) {                // ---- f2b W_in (float4 per thread)
        int i = (bid - 4096) * 256 + tid;
        float4 v = reinterpret_cast<const float4*>(W_in)[i];
        short4 o;
        o.x = f2bs(v.x); o.y = f2bs(v.y); o.z = f2bs(v.z); o.w = f2bs(v.w);
        reinterpret_cast<short4*>(wInb)[i] = o;
    } else if (bid < 8448) {                // ---- xpw 96x2048 -> padded 128x2048 bf16
        int i = (bid - 8192) * 256 + tid;
        int row = i >> 9;
        short4 o;
        if (row < 96) {
            float4 v = reinterpret_cast<const float4*>(xpw)[i];
            o.x = f2bs(v.x); o.y = f2bs(v.y); o.z = f2bs(v.z); o.w = f2bs(v.w);
        } else { o.x = o.y = o.z = o.w = 0; }
        reinterpret_cast<short4*>(xpwb)[i] = o;
    } else if (bid < 8576) {                // ---- f2b dtw
        int i = (bid - 8448) * 256 + tid;
        float4 v = reinterpret_cast<const float4*>(dtw)[i];
        short4 o;
        o.x = f2bs(v.x); o.y = f2bs(v.y); o.z = f2bs(v.z); o.w = f2bs(v.w);
        reinterpret_cast<short4*>(dtwb)[i] = o;
    } else {                                // ---- zero xdbl
        int i = (bid - 8576) * 256 + tid;
        reinterpret_cast<float4*>(xdbl)[i] = (float4){0.f, 0.f, 0.f, 0.f};
    }
}

// ---------------------------------------------------------------- fp32 -> bf16 convert
__global__ void k_f2b(const float* __restrict__ in, short* __restrict__ out) {
    int i = blockIdx.x * 256 + threadIdx.x;
    float4 v = reinterpret_cast<const float4*>(in)[i];
    short4 o;
    o.x = f2bs(v.x); o.y = f2bs(v.y); o.z = f2bs(v.z); o.w = f2bs(v.w);
    reinterpret_cast<short4*>(out)[i] = o;
}

// --------------------------------------------- dr = xdbl[:, 0:64] -> bf16 (4096x64)
__global__ void k_extract_dr(const float* __restrict__ xdbl, short* __restrict__ drb) {
    int i = blockIdx.x * 256 + threadIdx.x;
    int t = i >> 4;
    int jg = (i & 15) * 4;
    float4 v = *reinterpret_cast<const float4*>(&xdbl[(size_t)t * XDS + jg]);
    short4 o;
    o.x = f2bs(v.x); o.y = f2bs(v.y); o.z = f2bs(v.z); o.w = f2bs(v.w);
    *reinterpret_cast<short4*>(&drb[(size_t)t * DTRANK + jg]) = o;
}

// ---------------------------------------------------------------- MFMA GEMM (NT=64)
// m97-style 128 x 64 block tile, BK=32, double-buffered single-barrier K-loop.
// Used for the skinny GEMMs (xproj N=128, delta K=64).
// mode 2: atomicAdd(Cf, acc)                      (xproj, split-K via blockIdx.z)
// mode 3: Cf = softplus(acc + bias[col]) fp32     (delta)
#define GBK 32
template<int NT>
__global__ __launch_bounds__(256) void k_gemm_mfma(
    const short* __restrict__ A, const short* __restrict__ Bw,
    int N, int K, int mode,
    float* __restrict__ Cf, bf16* __restrict__ Cz,
    const float* __restrict__ res, float* __restrict__ Cout,
    const float* __restrict__ bias)
{
    constexpr int ABUF = 128 * GBK;            // shorts per A buffer (8 KB)
    constexpr int BBUF = NT * GBK;             // shorts per B buffer
    constexpr int AF   = (NT == 128) ? 4 : 2;  // row frags per wave
    __shared__ short As[2 * ABUF];
    __shared__ short Bs[2 * BBUF];
    const int tid  = threadIdx.x;
    const int lane = tid & 63;
    const int wave = tid >> 6;
    const int rowbase = (NT == 128) ? (wave >> 1) * 64 : wave * 32;
    const int colbase = (NT == 128) ? (wave & 1) * 64 : 0;
    const int m0 = blockIdx.y * 128;
    const int n0 = blockIdx.x * NT;
    const int lm = lane & 15;
    const int koff = (((lane >> 4) ^ ((lane >> 1) & 3)) * 8);

    const int srow = tid >> 2;                              // 0..63
    const int skc  = (((tid & 3) ^ ((tid >> 3) & 3)) * 8);  // swizzled source chunk
    const size_t a_off0 = (size_t)(m0 + srow) * K + skc;
    const size_t a_off1 = (size_t)(m0 + srow + 64) * K + skc;
    const size_t b_off0 = (size_t)(n0 + srow) * K + skc;
    size_t b_off1 = 0;
    if constexpr (NT == 128) b_off1 = (size_t)(n0 + srow + 64) * K + skc;

    f32x4 acc[AF][4];
#pragma unroll
    for (int i = 0; i < AF; ++i)
#pragma unroll
        for (int j = 0; j < 4; ++j)
            acc[i][j] = (f32x4){0.f, 0.f, 0.f, 0.f};

    const int kchunk = K / gridDim.z;
    const int kbeg = blockIdx.z * kchunk;
    const int kend = kbeg + kchunk;

    // prologue: tile 0 into buffer 0
    {
        char* aD = (char*)As + tid * 16;
        char* bD = (char*)Bs + tid * 16;
        async_copy16(A + a_off0 + kbeg, aD);
        async_copy16(A + a_off1 + kbeg, aD + 4096);
        async_copy16(Bw + b_off0 + kbeg, bD);
        if constexpr (NT == 128) async_copy16(Bw + b_off1 + kbeg, bD + 4096);
    }

    int cur = 0;
    for (int k0 = kbeg; k0 < kend; k0 += GBK) {
        __syncthreads();   // buf[cur] ready; compute on buf[cur^1] done
        int k1 = k0 + GBK;
        if (k1 < kend) {
            int nxt = cur ^ 1;
            char* aD = (char*)As + nxt * (ABUF * 2) + tid * 16;
            char* bD = (char*)Bs + nxt * (BBUF * 2) + tid * 16;
            async_copy16(A + a_off0 + k1, aD);
            async_copy16(A + a_off1 + k1, aD + 4096);
            async_copy16(Bw + b_off0 + k1, bD);
            if constexpr (NT == 128) async_copy16(Bw + b_off1 + k1, bD + 4096);
        }

        const short* Ab = As + cur * ABUF;
        const short* Bb = Bs + cur * BBUF;
        short8 af[AF], bf[4];
#pragma unroll
        for (int t = 0; t < AF; ++t)
            af[t] = *reinterpret_cast<const short8*>(&Ab[(rowbase + t * 16 + lm) * GBK + koff]);
#pragma unroll
        for (int t = 0; t < 4; ++t)
            bf[t] = *reinterpret_cast<const short8*>(&Bb[(colbase + t * 16 + lm) * GBK + koff]);
#pragma unroll
        for (int tm = 0; tm < AF; ++tm)
#pragma unroll
            for (int tn = 0; tn < 4; ++tn)
                acc[tm][tn] = __builtin_amdgcn_mfma_f32_16x16x32_bf16(
                    af[tm], bf[tn], acc[tm][tn], 0, 0, 0);
        cur ^= 1;
    }

    const int rq = (lane >> 4) * 4;
#pragma unroll
    for (int tm = 0; tm < AF; ++tm) {
#pragma unroll
        for (int tn = 0; tn < 4; ++tn) {
            f32x4 v = acc[tm][tn];
            int col = n0 + colbase + tn * 16 + lm;
#pragma unroll
            for (int r = 0; r < 4; ++r) {
                int row = m0 + rowbase + tm * 16 + rq + r;
                float val = v[r];
                if (mode == 0) {
                    if (col < D_INNER) Cf[(size_t)row * D_INNER + col] = val;
                    else               Cz[(size_t)row * D_INNER + (col - D_INNER)] = f2b(val);
                } else if (mode == 1) {
                    Cout[(size_t)row * N + col] = val + res[(size_t)row * N + col];
                } else if (mode == 2) {
                    atomicAdd(&Cf[(size_t)row * N + col], val);
                } else if (mode == 3) {
                    float a = val + bias[col];
                    float sp = (a > 20.f) ? a : log1pf(expf(a));
                    Cf[(size_t)row * N + col] = sp;
                } else {
                    Cf[(size_t)blockIdx.z * 4096 * N + (size_t)row * N + col] = val;
                }
            }
        }
    }
}

// ---------------------------------------------------------------- 8-phase BMx256 GEMM
// T1+T2+T3+T4+T5 schedule (plain-HIP port of the 256^2 8-phase template),
// templated on BM (256 for in-proj, 128 for out-proj parallelism).
// 512 threads = 8 waves (2M x 4N); wave tile (BM/2) x 64; BK=64; 2 LDS buffers,
// staging runs ~1.5 K-tiles ahead at half-tile granularity; vmcnt(4) once per
// K-tile (never 0 in steady state). LDS XOR-swizzle (16B chunk ^= row&7) with
// the inverse swizzle pre-applied to the per-lane GLOBAL source (both-sides rule).
// Per K-tile: 4 phases = C-quadrants (0,0),(0,1),(1,1),(1,0); MQ*2*2 MFMA each.
// Bijective XCD swizzle on the (x,y) grid (requires gridDim.x*gridDim.y % 8 == 0).
// mode 0: split at D_INNER -> Cf fp32 / Cz bf16   (in-proj)
// mode 4: Cf[z*4096*N + row*N + col] = acc        (split-K partials, out-proj)
template<int BM>
__global__ __launch_bounds__(512, 2) void k_gemm8(
    const short* __restrict__ A, const short* __restrict__ Bw,
    int N, int K, int mode,
    float* __restrict__ Cf, bf16* __restrict__ Cz)
{
    constexpr int WM    = BM / 2;        // wave rows
    constexpr int MQ    = WM / 32;       // m-frags per quadrant (4 for BM=256, 2 for BM=128)
    constexpr int ATILE = BM * 64;       // shorts per A buffer tile
    constexpr int ABYT  = BM * 128;      // bytes per A buffer tile
    constexpr int BREG  = BM * 256;      // byte offset of B region (2 A buffers)
    __shared__ short lds[2 * ATILE + 2 * 16384];
    char* ldsc = (char*)lds;
    const int tid  = threadIdx.x;
    const int lane = tid & 63;
    const int wave = tid >> 6;     // 0..7
    const int wr   = wave >> 2;    // 0..1  (row half of the BM-row tile)
    const int wc   = wave & 3;     // 0..3  (64-col slice of the 256-col tile)
    const int lm   = lane & 15;
    const int q4   = lane >> 4;

    // bijective XCD swizzle over the x-y plane (nwg % 8 == 0 at all call sites)
    const int gx = gridDim.x;
    int n2 = blockIdx.y * gx + blockIdx.x;
    const int nwg = gx * gridDim.y;
    n2 = (n2 & 7) * (nwg >> 3) + (n2 >> 3);
    const int m0 = (n2 / gx) * BM;
    const int n0 = (n2 % gx) * 256;

    // staging geometry: thread covers LDS bytes tid*16 (+8192) of a 16 KB half-tile
    const int r0  = tid >> 3;                        // LDS row 0..63 (and +64)
    const int ksw = ((tid & 7) ^ (r0 & 7)) << 3;     // inverse-swizzled source chunk (shorts)

    const int NTt   = K / 64 / gridDim.z;            // K-tiles in this split-K chunk
    const int kbase = blockIdx.z * NTt;

    const short* gA = A  + (size_t)(m0 + r0) * K + ksw;
    const short* gB = Bw + (size_t)(n0 + r0) * K + ksw;

#define STAGE_A8(h, kt, bb) do {                                             \
        const short* s_ = gA + (size_t)(h) * 128 * K + (size_t)(kt) * 64;    \
        char* d_ = ldsc + (bb) * ABYT + (h) * 16384 + tid * 16;              \
        async_copy16(s_, d_);                                                \
        async_copy16(s_ + (size_t)64 * K, d_ + 8192);                        \
    } while (0)
#define STAGE_B8(h, kt, bb) do {                                             \
        const short* s_ = gB + (size_t)(h) * 128 * K + (size_t)(kt) * 64;    \
        char* d_ = ldsc + BREG + (bb) * 32768 + (h) * 16384 + tid * 16;      \
        async_copy16(s_, d_);                                                \
        async_copy16(s_ + (size_t)64 * K, d_ + 8192);                        \
    } while (0)

    f32x4 acc[2][2][MQ][2];
#pragma unroll
    for (int a = 0; a < 2; ++a)
#pragma unroll
        for (int c = 0; c < 2; ++c)
#pragma unroll
            for (int t = 0; t < MQ; ++t)
#pragma unroll
                for (int u = 0; u < 2; ++u)
                    acc[a][c][t][u] = (f32x4){0.f, 0.f, 0.f, 0.f};

    // prologue: B(0), A(0) -> buf0; B(1) -> buf1. Wait tile 0 (leave B(1) in flight).
    STAGE_B8(0, kbase + 0, 0); STAGE_B8(1, kbase + 0, 0);
    STAGE_A8(0, kbase + 0, 0);
    if constexpr (BM == 256) STAGE_A8(1, kbase + 0, 0);
    STAGE_B8(0, kbase + 1, 1); STAGE_B8(1, kbase + 1, 1);
    asm volatile("s_waitcnt vmcnt(4)" ::: "memory");
    __builtin_amdgcn_s_barrier();

    short8 af[MQ][2], bf0[2][2], bf1[2][2];

    for (int tt = 0; tt < NTt; ++tt) {
        const int b  = tt & 1;
        const int bn = b ^ 1;
        const short* lA = lds + b * ATILE + wr * (WM * 64);            // this wave's A half
        const short* lB = lds + BM * 128 + b * 16384 + (wc >> 1) * 8192; // this wave's B half
        const bool stA = (tt + 1 < NTt);
        const bool stB = (tt + 2 < NTt);

        // ---------------- P0: ld af(qr=0) + bf0(qc=0); stage A-half0(tt+1)
#pragma unroll
        for (int t = 0; t < MQ; ++t) {
            const int rr = t * 16 + lm;
            const int x8 = rr & 7;
            af[t][0] = *reinterpret_cast<const short8*>(&lA[rr * 64 + ((q4 ^ x8) << 3)]);
            af[t][1] = *reinterpret_cast<const short8*>(&lA[rr * 64 + (((4 + q4) ^ x8) << 3)]);
        }
#pragma unroll
        for (int t = 0; t < 2; ++t) {
            const int rr = (wc & 1) * 64 + t * 16 + lm;
            const int x8 = rr & 7;
            bf0[t][0] = *reinterpret_cast<const short8*>(&lB[rr * 64 + ((q4 ^ x8) << 3)]);
            bf0[t][1] = *reinterpret_cast<const short8*>(&lB[rr * 64 + (((4 + q4) ^ x8) << 3)]);
        }
        if (stA) STAGE_A8(0, kbase + tt + 1, bn);
        __builtin_amdgcn_s_barrier();
        asm volatile("s_waitcnt lgkmcnt(0)" ::: "memory");
        __builtin_amdgcn_s_setprio(1);
#pragma unroll
        for (int t = 0; t < MQ; ++t)
#pragma unroll
            for (int u = 0; u < 2; ++u) {
                acc[0][0][t][u] = __builtin_amdgcn_mfma_f32_16x16x32_bf16(af[t][0], bf0[u][0], acc[0][0][t][u], 0, 0, 0);
                acc[0][0][t][u] = __builtin_amdgcn_mfma_f32_16x16x32_bf16(af[t][1], bf0[u][1], acc[0][0][t][u], 0, 0, 0);
            }
        __builtin_amdgcn_s_setprio(0);
        __builtin_amdgcn_s_barrier();

        // ---------------- P1: ld bf1(qc=1); stage A-half1(tt+1); compute (0,1)
#pragma unroll
        for (int t = 0; t < 2; ++t) {
            const int rr = (wc & 1) * 64 + 32 + t * 16 + lm;
            const int x8 = rr & 7;
            bf1[t][0] = *reinterpret_cast<const short8*>(&lB[rr * 64 + ((q4 ^ x8) << 3)]);
            bf1[t][1] = *reinterpret_cast<const short8*>(&lB[rr * 64 + (((4 + q4) ^ x8) << 3)]);
        }
        if constexpr (BM == 256) { if (stA) STAGE_A8(1, kbase + tt + 1, bn); }
        __builtin_amdgcn_s_barrier();
        asm volatile("s_waitcnt lgkmcnt(0)" ::: "memory");
        __builtin_amdgcn_s_setprio(1);
#pragma unroll
        for (int t = 0; t < MQ; ++t)
#pragma unroll
            for (int u = 0; u < 2; ++u) {
                acc[0][1][t][u] = __builtin_amdgcn_mfma_f32_16x16x32_bf16(af[t][0], bf1[u][0], acc[0][1][t][u], 0, 0, 0);
                acc[0][1][t][u] = __builtin_amdgcn_mfma_f32_16x16x32_bf16(af[t][1], bf1[u][1], acc[0][1][t][u], 0, 0, 0);
            }
        __builtin_amdgcn_s_setprio(0);
        __builtin_amdgcn_s_barrier();

        // ---------------- P2: ld af(qr=1); stage B-half0(tt+2); compute (1,1)
#pragma unroll
        for (int t = 0; t < MQ; ++t) {
            const int rr = MQ * 16 + t * 16 + lm;
            const int x8 = rr & 7;
            af[t][0] = *reinterpret_cast<const short8*>(&lA[rr * 64 + ((q4 ^ x8) << 3)]);
            af[t][1] = *reinterpret_cast<const short8*>(&lA[rr * 64 + (((4 + q4) ^ x8) << 3)]);
        }
        if (stB) STAGE_B8(0, kbase + tt + 2, b);
        __builtin_amdgcn_s_barrier();
        asm volatile("s_waitcnt lgkmcnt(0)" ::: "memory");
        __builtin_amdgcn_s_setprio(1);
#pragma unroll
        for (int t = 0; t < MQ; ++t)
#pragma unroll
            for (int u = 0; u < 2; ++u) {
                acc[1][1][t][u] = __builtin_amdgcn_mfma_f32_16x16x32_bf16(af[t][0], bf1[u][0], acc[1][1][t][u], 0, 0, 0);
                acc[1][1][t][u] = __builtin_amdgcn_mfma_f32_16x16x32_bf16(af[t][1], bf1[u][1], acc[1][1][t][u], 0, 0, 0);
            }
        __builtin_amdgcn_s_setprio(0);
        __builtin_amdgcn_s_barrier();

        // ---------------- P3: stage B-half1(tt+2); vmcnt; compute (1,0) with bf0
        if (stB) {
            STAGE_B8(1, kbase + tt + 2, b);
            asm volatile("s_waitcnt vmcnt(4)" ::: "memory");   // tile tt+1 fully landed
        } else if (stA) {
            asm volatile("s_waitcnt vmcnt(0)" ::: "memory");   // drain A(NTt-1)
        }
        __builtin_amdgcn_s_barrier();
        __builtin_amdgcn_s_setprio(1);
#pragma unroll
        for (int t = 0; t < MQ; ++t)
#pragma unroll
            for (int u = 0; u < 2; ++u) {
                acc[1][0][t][u] = __builtin_amdgcn_mfma_f32_16x16x32_bf16(af[t][0], bf0[u][0], acc[1][0][t][u], 0, 0, 0);
                acc[1][0][t][u] = __builtin_amdgcn_mfma_f32_16x16x32_bf16(af[t][1], bf0[u][1], acc[1][0][t][u], 0, 0, 0);
            }
        __builtin_amdgcn_s_setprio(0);
        __builtin_amdgcn_s_barrier();
    }
#undef STAGE_A8
#undef STAGE_B8

    // -------- epilogue
    const int rq = (lane >> 4) * 4;
#pragma unroll
    for (int qr = 0; qr < 2; ++qr)
#pragma unroll
    for (int qc = 0; qc < 2; ++qc)
#pragma unroll
    for (int t = 0; t < MQ; ++t)
#pragma unroll
    for (int u = 0; u < 2; ++u) {
        f32x4 v = acc[qr][qc][t][u];
        const int col = n0 + wc * 64 + qc * 32 + u * 16 + lm;
#pragma unroll
        for (int r = 0; r < 4; ++r) {
            const int row = m0 + wr * WM + qr * (WM / 2) + t * 16 + rq + r;
            if (mode == 0) {
                if (col < D_INNER) Cf[(size_t)row * D_INNER + col] = v[r];
                else               Cz[(size_t)row * D_INNER + (col - D_INNER)] = f2b(v[r]);
            } else {
                Cf[(size_t)blockIdx.z * 4096 * N + (size_t)row * N + col] = v[r];
            }
        }
    }
}

// ------------------------------------------------- out = x + P0 + P1 (out-proj reduce)
__global__ void k_reduce_out(const float* __restrict__ x, const float* __restrict__ P,
                             float* __restrict__ out) {
    int i = blockIdx.x * 256 + threadIdx.x;
    float4 a = reinterpret_cast<const float4*>(x)[i];
    float4 p = reinterpret_cast<const float4*>(P)[i];
    float4 q = reinterpret_cast<const float4*>(P + (size_t)4096 * 1024)[i];
    float4 o;
    o.x = a.x + p.x + q.x; o.y = a.y + p.y + q.y;
    o.z = a.z + p.z + q.z; o.w = a.w + p.w + q.w;
    reinterpret_cast<float4*>(out)[i] = o;
}

// ------------------------------------------------- causal depthwise conv + SiLU
__global__ void k_conv(const float* __restrict__ xc, const float* __restrict__ cw,
                       const float* __restrict__ cb, bf16* __restrict__ xcs) {
    size_t idx = (size_t)blockIdx.x * blockDim.x + threadIdx.x;
    int d = (int)(idx & (D_INNER - 1));
    int l = (int)((idx >> 11) & (SEQ - 1));
    float w0 = cw[d * 4 + 0], w1 = cw[d * 4 + 1];
    float w2 = cw[d * 4 + 2], w3 = cw[d * 4 + 3];
    const float* base = xc + idx;
    float acc = cb[d] + w3 * base[0];
    if (l >= 1) acc += w2 * base[-(int)D_INNER];
    if (l >= 2) acc += w1 * base[-2 * (int)D_INNER];
    if (l >= 3) acc += w0 * base[-3 * (int)D_INNER];
    xcs[idx] = f2b(acc / (1.f + __expf(-acc)));   // silu
}

// ------------------------------------------------- scan pass A: per-chunk partials
__global__ __launch_bounds__(256) void k_scan_partialB(
    const float* __restrict__ delta, const bf16* __restrict__ xcs,
    const float* __restrict__ xdbl, const float* __restrict__ A_log,
    bf16* __restrict__ chs, float* __restrict__ sumdl)
{
    __shared__ float Bsh[CHLEN][16];
    const int tid = threadIdx.x;
    const int d = blockIdx.x * 256 + tid;
    const int chunk = blockIdx.y;
    const int b = blockIdx.z;
    const size_t tbase = (size_t)b * SEQ + (size_t)chunk * CHLEN;

    if (tid < 128) {
        int t = tid >> 2, j = (tid & 3) * 4;
        float4 v = *reinterpret_cast<const float4*>(&xdbl[(tbase + t) * XDS + 64 + j]);
        *reinterpret_cast<float4*>(&Bsh[t][j]) = v;
    }
    float An[16];
#pragma unroll
    for (int j = 0; j < 4; ++j) {
        float4 v = *reinterpret_cast<const float4*>(&A_log[(size_t)d * DSTATE + j * 4]);
        An[j * 4 + 0] = -__expf(v.x); An[j * 4 + 1] = -__expf(v.y);
        An[j * 4 + 2] = -__expf(v.z); An[j * 4 + 3] = -__expf(v.w);
    }
    __syncthreads();

    float s[16];
#pragma unroll
    for (int n = 0; n < 16; ++n) s[n] = 0.f;
    float sd = 0.f;
    for (int t = 0; t < CHLEN; ++t) {
        size_t gt = tbase + t;
        float dl = delta[gt * D_INNER + d];
        float u  = b2f(xcs[gt * D_INNER + d]);
        float dlu = dl * u;
        sd += dl;
#pragma unroll
        for (int n = 0; n < 16; ++n) {
            float dA = __expf(dl * An[n]);
            s[n] = fmaf(dA, s[n], dlu * Bsh[t][n]);
        }
    }
    const int pair = b * D_INNER + d;
    bf16* co = chs + ((size_t)pair * NCH + chunk) * DSTATE;
#pragma unroll
    for (int n = 0; n < 16; ++n) co[n] = f2b(s[n]);
    sumdl[(size_t)pair * NCH + chunk] = sd;
}

// ------------------------------------------------- scan pass B: chunk-prefix combine
// sst ALIASES chs: read chunk-sum before writing entry state (same thread+element).
__global__ void k_scan_combineB(const bf16* __restrict__ chs, const float* __restrict__ sumdl,
                                const float* __restrict__ A_log, bf16* __restrict__ sst) {
    int idx = blockIdx.x * 256 + threadIdx.x;
    int pair = idx >> 4;
    int n = idx & 15;
    int d = pair & (D_INNER - 1);
    float An = -__expf(A_log[(size_t)d * DSTATE + n]);
    float s = 0.f;
    for (int c = 0; c < NCH; ++c) {
        size_t o = ((size_t)pair * NCH + c) * DSTATE + n;
        float loc = b2f(chs[o]);
        float ap = __expf(An * sumdl[(size_t)pair * NCH + c]);
        sst[o] = f2b(s);
        s = fmaf(ap, s, loc);
    }
}

// ------------------------------------------------- scan pass C: final y + gate
// yf aliases zbuf elementwise (same-thread read-then-write).
__global__ __launch_bounds__(256) void k_scan_finalB(
    const float* __restrict__ delta, const bf16* __restrict__ xcs,
    const float* __restrict__ xdbl, const bf16* __restrict__ zbuf,
    const float* __restrict__ A_log, const float* __restrict__ Dp,
    const bf16* __restrict__ sst, bf16* __restrict__ yf)
{
    __shared__ float BC[CHLEN][32];   // [t][0:16]=B, [t][16:32]=C
    const int tid = threadIdx.x;
    const int d = blockIdx.x * 256 + tid;
    const int chunk = blockIdx.y;
    const int b = blockIdx.z;
    const size_t tbase = (size_t)b * SEQ + (size_t)chunk * CHLEN;

    {
        int t = tid >> 3, j = (tid & 7) * 4;
        float4 v = *reinterpret_cast<const float4*>(&xdbl[(tbase + t) * XDS + 64 + j]);
        *reinterpret_cast<float4*>(&BC[t][j]) = v;
    }
    float An[16];
#pragma unroll
    for (int j = 0; j < 4; ++j) {
        float4 v = *reinterpret_cast<const float4*>(&A_log[(size_t)d * DSTATE + j * 4]);
        An[j * 4 + 0] = -__expf(v.x); An[j * 4 + 1] = -__expf(v.y);
        An[j * 4 + 2] = -__expf(v.z); An[j * 4 + 3] = -__expf(v.w);
    }
    const int pair = b * D_INNER + d;
    float s[16];
    const bf16* so = sst + ((size_t)pair * NCH + chunk) * DSTATE;
#pragma unroll
    for (int n = 0; n < 16; ++n) s[n] = b2f(so[n]);
    const float Dv = Dp[d];
    __syncthreads();

    for (int t = 0; t < CHLEN; ++t) {
        size_t gt = tbase + t;
        float dl = delta[gt * D_INNER + d];
        float u  = b2f(xcs[gt * D_INNER + d]);
        float dlu = dl * u;
        float y = 0.f;
#pragma unroll
        for (int n = 0; n < 16; ++n) {
            float dA = __expf(dl * An[n]);
            s[n] = fmaf(dA, s[n], dlu * BC[t][n]);
            y = fmaf(s[n], BC[t][16 + n], y);
        }
        float zv = b2f(zbuf[gt * D_INNER + d]);
        float sz = zv / (1.f + __expf(-zv));
        yf[gt * D_INNER + d] = f2b((y + u * Dv) * sz);
    }
}

// ---------------------------------------------------------------- launch
extern "C" void kernel_launch(void* const* d_in, const int* in_sizes, int n_in,
                              void* d_out, int out_size, void* d_ws, size_t ws_size,
                              hipStream_t stream) {
    const float* x      = (const float*)d_in[0];
    const float* ln_g   = (const float*)d_in[1];
    const float* ln_b   = (const float*)d_in[2];
    const float* W_in   = (const float*)d_in[3];
    const float* conv_w = (const float*)d_in[4];
    const float* conv_b = (const float*)d_in[5];
    const float* A_log  = (const float*)d_in[6];
    const float* D_par  = (const float*)d_in[7];
    const float* xpw    = (const float*)d_in[8];
    const float* dtw    = (const float*)d_in[9];
    const float* dtb    = (const float*)d_in[10];
    const float* W_out  = (const float*)d_in[11];
    float* out = (float*)d_out;

    char* ws = (char*)d_ws;
    // workspace (79,953,920 B), stage-lifetime aliased:
    //  [0,        8388608)  xn bf16 -> chs/sst bf16 (scan) -> wOutb bf16 (after scan_final)
    //  [8388608, 41943040)  xc fp32 -> delta fp32 -> P0 fp32 @8388608 + P1 fp32 @25165824
    //  [41943040,58720256)  z bf16  <- yf aliases z
    //  [58720256,75497472)  wInb bf16 -> xcs bf16
    //  [75497472,77594624)  xdbl fp32 (4096x128)
    //  [77594624,78643200)  sumdl; [78643200..] drb, dtwb, xpwb
    bf16*  xn    = (bf16*)(ws + 0);
    bf16*  chs   = (bf16*)(ws + 0);
    bf16*  sst   = chs;
    short* wOutb = (short*)(ws + 0);           // after scan kernels are done
    float* xc    = (float*)(ws + 8388608);
    float* delta = xc;
    float* P0    = (float*)(ws + 8388608);     // after delta is dead (post scan_final)
    bf16*  z     = (bf16*)(ws + 41943040);
    bf16*  yf    = z;
    short* wInb  = (short*)(ws + 58720256);
    bf16*  xcs   = (bf16*)(ws + 58720256);
    float* xdbl  = (float*)(ws + 75497472);
    float* sumdl = (float*)(ws + 77594624);
    short* drb   = (short*)(ws + 78643200);
    short* dtwb  = (short*)(ws + 79167488);
    short* xpwb  = (short*)(ws + 79429632);

    // fused prep: LN + f2b(W_in) + prep(xpw) + f2b(dtw) + zero(xdbl)
    k_prep<<<9088, 256, 0, stream>>>(x, ln_g, ln_b, xn, W_in, wInb, xpw, xpwb, dtw, dtwb, xdbl);
    // in-proj GEMM: 4096 x 4096 x 1024, 8-phase 256^2 -> 256 blocks (1/CU)
    k_gemm8<256><<<dim3(4096 / 256, 4096 / 256, 1), 512, 0, stream>>>(
        (const short*)xn, wInb, 2 * D_INNER, D_MODEL, 0, xc, z);
    k_conv<<<(NTOK * D_INNER) / 256, 256, 0, stream>>>(xc, conv_w, conv_b, xcs);
    // xproj GEMM: 4096 x 128 x 2048, NT=64, split-K=8 atomic -> 512 blocks
    k_gemm_mfma<64><<<dim3(2, 32, 8), 256, 0, stream>>>(
        (const short*)xcs, xpwb, XDS, D_INNER, 2, xdbl, nullptr, nullptr, nullptr, nullptr);
    // delta GEMM: 4096 x 2048 x 64, NT=64 -> 1024 blocks, softplus epilogue
    k_extract_dr<<<(NTOK * DTRANK / 4) / 256, 256, 0, stream>>>(xdbl, drb);
    k_gemm_mfma<64><<<dim3(D_INNER / 64, 32, 1), 256, 0, stream>>>(
        drb, dtwb, D_INNER, DTRANK, 3, delta, nullptr, nullptr, nullptr, dtb);
    // selective scan (3-pass, register-state formulation)
    k_scan_partialB<<<dim3(D_INNER / 256, NCH, BSZ), 256, 0, stream>>>(
        delta, xcs, xdbl, A_log, chs, sumdl);
    k_scan_combineB<<<(NPAIR * DSTATE) / 256, 256, 0, stream>>>(chs, sumdl, A_log, sst);
    k_scan_finalB<<<dim3(D_INNER / 256, NCH, BSZ), 256, 0, stream>>>(
        delta, xcs, xdbl, z, A_log, D_par, sst, yf);
    // out-proj GEMM: 4096 x 1024 x 2048, 8-phase 128x256 split-K=2 -> 256 blocks + reduce
    k_f2b<<<(D_MODEL * D_INNER / 4) / 256, 256, 0, stream>>>(W_out, wOutb);
    k_gemm8<128><<<dim3(D_MODEL / 256, 4096 / 128, 2), 512, 0, stream>>>(
        (const short*)yf, wOutb, D_MODEL, D_INNER, 4, P0, nullptr);
    k_reduce_out<<<(NTOK * D_MODEL / 4) / 256, 256, 0, stream>>>(x, P0, out);
}

// Round 4
// 350.790 us; speedup vs baseline: 1.2335x; 1.0354x over previous
//
#include <hip/hip_runtime.h>
#include <hip/hip_bf16.h>
#include <math.h>

typedef __hip_bfloat16 bf16;

#define D_MODEL 1024
#define D_INNER 2048
#define NTOK    4096   // B*L
#define SEQ     2048
#define BSZ     2
#define DSTATE  16
#define DTRANK  64
#define NCH     64
#define CHLEN   32     // SEQ / NCH
#define NPAIR   4096   // BSZ * D_INNER
#define XDS     128    // xdbl row stride (fp32), padded from 96

__device__ __forceinline__ float b2f(bf16 v) { return __bfloat162float(v); }
__device__ __forceinline__ bf16  f2b(float v) { return __float2bfloat16(v); }
__device__ __forceinline__ short f2bs(float v) {
    bf16 h = __float2bfloat16(v);
    short s; __builtin_memcpy(&s, &h, 2); return s;
}

typedef __attribute__((ext_vector_type(8))) short short8;
typedef __attribute__((ext_vector_type(4))) float f32x4;

__device__ __forceinline__ void async_copy16(const void* g, void* l) {
    __builtin_amdgcn_global_load_lds(
        (const __attribute__((address_space(1))) unsigned int*)g,
        (__attribute__((address_space(3))) unsigned int*)l,
        16, 0, 0);
}

// ---------------------------------------------------------------- fused prep
// blocks [0,4096): LayerNorm; [4096,8192): f2b W_in; [8192,8448): prep xpw;
// [8448,8576): f2b dtw. Uniform branch per block.
__global__ void k_prep(const float* __restrict__ x, const float* __restrict__ g,
                       const float* __restrict__ b, bf16* __restrict__ xn,
                       const float* __restrict__ W_in, short* __restrict__ wInb,
                       const float* __restrict__ xpw, short* __restrict__ xpwb,
                       const float* __restrict__ dtw, short* __restrict__ dtwb) {
    int bid = blockIdx.x;
    int tid = threadIdx.x;
    if (bid < 4096) {                       // ---- LayerNorm, one block per token
        int t = bid;
        const float* row = x + (size_t)t * D_MODEL;
        float v[4];
        float s = 0.f, q = 0.f;
#pragma unroll
        for (int i = 0; i < 4; ++i) {
            int idx = tid + i * 256;
            v[i] = row[idx];
            s += v[i]; q += v[i] * v[i];
        }
        __shared__ float sh_s[256], sh_q[256];
        sh_s[tid] = s; sh_q[tid] = q;
        __syncthreads();
        for (int o = 128; o > 0; o >>= 1) {
            if (tid < o) { sh_s[tid] += sh_s[tid + o]; sh_q[tid] += sh_q[tid + o]; }
            __syncthreads();
        }
        float mu  = sh_s[0] * (1.f / D_MODEL);
        float var = sh_q[0] * (1.f / D_MODEL) - mu * mu;
        float rs  = rsqrtf(var + 1e-5f);
#pragma unroll
        for (int i = 0; i < 4; ++i) {
            int idx = tid + i * 256;
            float o = (v[i] - mu) * rs * g[idx] + b[idx];
            xn[(size_t)t * D_MODEL + idx] = f2b(o);
        }
    } else if (bid < 8192) {                // ---- f2b W_in (float4 per thread)
        int i = (bid - 4096) * 256 + tid;
        float4 v = reinterpret_cast<const float4*>(W_in)[i];
        short4 o;
        o.x = f2bs(v.x); o.y = f2bs(v.y); o.z = f2bs(v.z); o.w = f2bs(v.w);
        reinterpret_cast<short4*>(wInb)[i] = o;
    } else if (bid < 8448) {                // ---- xpw 96x2048 -> padded 128x2048 bf16
        int i = (bid - 8192) * 256 + tid;
        int row = i >> 9;
        short4 o;
        if (row < 96) {
            float4 v = reinterpret_cast<const float4*>(xpw)[i];
            o.x = f2bs(v.x); o.y = f2bs(v.y); o.z = f2bs(v.z); o.w = f2bs(v.w);
        } else { o.x = o.y = o.z = o.w = 0; }
        reinterpret_cast<short4*>(xpwb)[i] = o;
    } else {                                // ---- f2b dtw
        int i = (bid - 8448) * 256 + tid;
        float4 v = reinterpret_cast<const float4*>(dtw)[i];
        short4 o;
        o.x = f2bs(v.x); o.y = f2bs(v.y); o.z = f2bs(v.z); o.w = f2bs(v.w);
        reinterpret_cast<short4*>(dtwb)[i] = o;
    }
}

// ---------------------------------------------------------------- fp32 -> bf16 convert
__global__ void k_f2b(const float* __restrict__ in, short* __restrict__ out) {
    int i = blockIdx.x * 256 + threadIdx.x;
    float4 v = reinterpret_cast<const float4*>(in)[i];
    short4 o;
    o.x = f2bs(v.x); o.y = f2bs(v.y); o.z = f2bs(v.z); o.w = f2bs(v.w);
    reinterpret_cast<short4*>(out)[i] = o;
}

// --------------------------------------- xproj split-K reduce: sum 8 partials,
// cols 0:64 -> drb bf16 (delta-GEMM A), cols 64:128 -> xdbl fp32 (B/C for scan).
__global__ void k_xproj_red(const float* __restrict__ P, short* __restrict__ drb,
                            float* __restrict__ xdbl) {
    int i = blockIdx.x * 256 + threadIdx.x;   // 4096*32 threads, float4 each
    int t = i >> 5;
    int c4 = (i & 31) * 4;
    const float* p = P + (size_t)t * XDS + c4;
    float4 s = *reinterpret_cast<const float4*>(p);
#pragma unroll
    for (int z = 1; z < 8; ++z) {
        float4 v = *reinterpret_cast<const float4*>(p + (size_t)z * 4096 * XDS);
        s.x += v.x; s.y += v.y; s.z += v.z; s.w += v.w;
    }
    if (c4 < DTRANK) {
        short4 o;
        o.x = f2bs(s.x); o.y = f2bs(s.y); o.z = f2bs(s.z); o.w = f2bs(s.w);
        *reinterpret_cast<short4*>(&drb[(size_t)t * DTRANK + c4]) = o;
    } else {
        *reinterpret_cast<float4*>(&xdbl[(size_t)t * XDS + c4]) = s;
    }
}

// ---------------------------------------------------------------- MFMA GEMM (NT=64)
// m97-style 128 x 64 block tile, BK=32, double-buffered single-barrier K-loop.
// Used for the skinny GEMMs (xproj N=128, delta K=64).
// mode 3: Cf = softplus(acc + bias[col]) fp32     (delta)
// mode 4: Cf[z*4096*N + row*N + col] = acc        (xproj split-K partials)
#define GBK 32
template<int NT>
__global__ __launch_bounds__(256) void k_gemm_mfma(
    const short* __restrict__ A, const short* __restrict__ Bw,
    int N, int K, int mode,
    float* __restrict__ Cf, bf16* __restrict__ Cz,
    const float* __restrict__ res, float* __restrict__ Cout,
    const float* __restrict__ bias)
{
    constexpr int ABUF = 128 * GBK;            // shorts per A buffer (8 KB)
    constexpr int BBUF = NT * GBK;             // shorts per B buffer
    constexpr int AF   = (NT == 128) ? 4 : 2;  // row frags per wave
    __shared__ short As[2 * ABUF];
    __shared__ short Bs[2 * BBUF];
    const int tid  = threadIdx.x;
    const int lane = tid & 63;
    const int wave = tid >> 6;
    const int rowbase = (NT == 128) ? (wave >> 1) * 64 : wave * 32;
    const int colbase = (NT == 128) ? (wave & 1) * 64 : 0;
    const int m0 = blockIdx.y * 128;
    const int n0 = blockIdx.x * NT;
    const int lm = lane & 15;
    const int koff = (((lane >> 4) ^ ((lane >> 1) & 3)) * 8);

    const int srow = tid >> 2;                              // 0..63
    const int skc  = (((tid & 3) ^ ((tid >> 3) & 3)) * 8);  // swizzled source chunk
    const size_t a_off0 = (size_t)(m0 + srow) * K + skc;
    const size_t a_off1 = (size_t)(m0 + srow + 64) * K + skc;
    const size_t b_off0 = (size_t)(n0 + srow) * K + skc;
    size_t b_off1 = 0;
    if constexpr (NT == 128) b_off1 = (size_t)(n0 + srow + 64) * K + skc;

    f32x4 acc[AF][4];
#pragma unroll
    for (int i = 0; i < AF; ++i)
#pragma unroll
        for (int j = 0; j < 4; ++j)
            acc[i][j] = (f32x4){0.f, 0.f, 0.f, 0.f};

    const int kchunk = K / gridDim.z;
    const int kbeg = blockIdx.z * kchunk;
    const int kend = kbeg + kchunk;

    // prologue: tile 0 into buffer 0
    {
        char* aD = (char*)As + tid * 16;
        char* bD = (char*)Bs + tid * 16;
        async_copy16(A + a_off0 + kbeg, aD);
        async_copy16(A + a_off1 + kbeg, aD + 4096);
        async_copy16(Bw + b_off0 + kbeg, bD);
        if constexpr (NT == 128) async_copy16(Bw + b_off1 + kbeg, bD + 4096);
    }

    int cur = 0;
    for (int k0 = kbeg; k0 < kend; k0 += GBK) {
        __syncthreads();   // buf[cur] ready; compute on buf[cur^1] done
        int k1 = k0 + GBK;
        if (k1 < kend) {
            int nxt = cur ^ 1;
            char* aD = (char*)As + nxt * (ABUF * 2) + tid * 16;
            char* bD = (char*)Bs + nxt * (BBUF * 2) + tid * 16;
            async_copy16(A + a_off0 + k1, aD);
            async_copy16(A + a_off1 + k1, aD + 4096);
            async_copy16(Bw + b_off0 + k1, bD);
            if constexpr (NT == 128) async_copy16(Bw + b_off1 + k1, bD + 4096);
        }

        const short* Ab = As + cur * ABUF;
        const short* Bb = Bs + cur * BBUF;
        short8 af[AF], bf[4];
#pragma unroll
        for (int t = 0; t < AF; ++t)
            af[t] = *reinterpret_cast<const short8*>(&Ab[(rowbase + t * 16 + lm) * GBK + koff]);
#pragma unroll
        for (int t = 0; t < 4; ++t)
            bf[t] = *reinterpret_cast<const short8*>(&Bb[(colbase + t * 16 + lm) * GBK + koff]);
#pragma unroll
        for (int tm = 0; tm < AF; ++tm)
#pragma unroll
            for (int tn = 0; tn < 4; ++tn)
                acc[tm][tn] = __builtin_amdgcn_mfma_f32_16x16x32_bf16(
                    af[tm], bf[tn], acc[tm][tn], 0, 0, 0);
        cur ^= 1;
    }

    const int rq = (lane >> 4) * 4;
#pragma unroll
    for (int tm = 0; tm < AF; ++tm) {
#pragma unroll
        for (int tn = 0; tn < 4; ++tn) {
            f32x4 v = acc[tm][tn];
            int col = n0 + colbase + tn * 16 + lm;
#pragma unroll
            for (int r = 0; r < 4; ++r) {
                int row = m0 + rowbase + tm * 16 + rq + r;
                float val = v[r];
                if (mode == 0) {
                    if (col < D_INNER) Cf[(size_t)row * D_INNER + col] = val;
                    else               Cz[(size_t)row * D_INNER + (col - D_INNER)] = f2b(val);
                } else if (mode == 1) {
                    Cout[(size_t)row * N + col] = val + res[(size_t)row * N + col];
                } else if (mode == 2) {
                    atomicAdd(&Cf[(size_t)row * N + col], val);
                } else if (mode == 3) {
                    float a = val + bias[col];
                    float sp = (a > 20.f) ? a : log1pf(expf(a));
                    Cf[(size_t)row * N + col] = sp;
                } else {
                    Cf[(size_t)blockIdx.z * 4096 * N + (size_t)row * N + col] = val;
                }
            }
        }
    }
}

// ---------------------------------------------------------------- relaxed BMx256 GEMM
// Free-running 2-barrier-per-K-tile schedule: counted vmcnt(4) (never drains in
// steady state), NO lgkmcnt(0) waits (compiler emits precise per-dep counted
// waits), waves drift within each half-tile region so DS-read and MFMA pipes
// overlap across waves. 512 threads = 8 waves (2M x 4N); wave tile (BM/2) x 64;
// BK=64; LDS XOR-swizzle with inverse pre-applied to global source.
// Buffer lifetimes per tile tt (b=tt&1): reads only buf[b]; A(tt+1)->A[bn]
// (untouched this tile); B(tt+2)->B[b] AFTER the mid barrier (all bf reads of
// B[b] already in registers). vmcnt(4) at tile end => A(tt+1),B(tt+1) landed,
// B(tt+2) still in flight.
// mode 0: split at D_INNER -> Cf fp32 / Cz bf16   (in-proj)
// mode 4: Cf[z*4096*N + row*N + col] = acc        (split-K partials, out-proj)
template<int BM>
__global__ __launch_bounds__(512, 2) void k_gemm8(
    const short* __restrict__ A, const short* __restrict__ Bw,
    int N, int K, int mode,
    float* __restrict__ Cf, bf16* __restrict__ Cz)
{
    constexpr int WM    = BM / 2;        // wave rows
    constexpr int MQ    = WM / 32;       // m-frags per quadrant (4 for BM=256, 2 for BM=128)
    constexpr int ATILE = BM * 64;       // shorts per A buffer tile
    constexpr int ABYT  = BM * 128;      // bytes per A buffer tile
    constexpr int BREG  = BM * 256;      // byte offset of B region (2 A buffers)
    __shared__ short lds[2 * ATILE + 2 * 16384];
    char* ldsc = (char*)lds;
    const int tid  = threadIdx.x;
    const int lane = tid & 63;
    const int wave = tid >> 6;     // 0..7
    const int wr   = wave >> 2;    // 0..1  (row half of the BM-row tile)
    const int wc   = wave & 3;     // 0..3  (64-col slice of the 256-col tile)
    const int lm   = lane & 15;
    const int q4   = lane >> 4;

    // bijective XCD swizzle over the x-y plane (nwg % 8 == 0 at all call sites)
    const int gx = gridDim.x;
    int n2 = blockIdx.y * gx + blockIdx.x;
    const int nwg = gx * gridDim.y;
    n2 = (n2 & 7) * (nwg >> 3) + (n2 >> 3);
    const int m0 = (n2 / gx) * BM;
    const int n0 = (n2 % gx) * 256;

    // staging geometry: thread covers LDS bytes tid*16 (+8192) of a 16 KB half-tile
    const int r0  = tid >> 3;                        // LDS row 0..63 (and +64)
    const int ksw = ((tid & 7) ^ (r0 & 7)) << 3;     // inverse-swizzled source chunk (shorts)

    const int NTt   = K / 64 / gridDim.z;            // K-tiles in this split-K chunk
    const int kbase = blockIdx.z * NTt;

    const short* gA = A  + (size_t)(m0 + r0) * K + ksw;
    const short* gB = Bw + (size_t)(n0 + r0) * K + ksw;

#define STAGE_A8(h, kt, bb) do {                                             \
        const short* s_ = gA + (size_t)(h) * 128 * K + (size_t)(kt) * 64;    \
        char* d_ = ldsc + (bb) * ABYT + (h) * 16384 + tid * 16;              \
        async_copy16(s_, d_);                                                \
        async_copy16(s_ + (size_t)64 * K, d_ + 8192);                        \
    } while (0)
#define STAGE_B8(h, kt, bb) do {                                             \
        const short* s_ = gB + (size_t)(h) * 128 * K + (size_t)(kt) * 64;    \
        char* d_ = ldsc + BREG + (bb) * 32768 + (h) * 16384 + tid * 16;      \
        async_copy16(s_, d_);                                                \
        async_copy16(s_ + (size_t)64 * K, d_ + 8192);                        \
    } while (0)

    f32x4 acc[2][2][MQ][2];
#pragma unroll
    for (int a = 0; a < 2; ++a)
#pragma unroll
        for (int c = 0; c < 2; ++c)
#pragma unroll
            for (int t = 0; t < MQ; ++t)
#pragma unroll
                for (int u = 0; u < 2; ++u)
                    acc[a][c][t][u] = (f32x4){0.f, 0.f, 0.f, 0.f};

    // prologue: B(0), A(0) -> buf0; B(1) -> buf1. Wait tile 0 (leave B(1) in flight).
    STAGE_B8(0, kbase + 0, 0); STAGE_B8(1, kbase + 0, 0);
    STAGE_A8(0, kbase + 0, 0);
    if constexpr (BM == 256) STAGE_A8(1, kbase + 0, 0);
    STAGE_B8(0, kbase + 1, 1); STAGE_B8(1, kbase + 1, 1);
    asm volatile("s_waitcnt vmcnt(4)" ::: "memory");
    __builtin_amdgcn_s_barrier();
    __builtin_amdgcn_sched_barrier(0);

    short8 af[MQ][2], bf0[2][2], bf1[2][2];

    for (int tt = 0; tt < NTt; ++tt) {
        const int b  = tt & 1;
        const int bn = b ^ 1;
        const short* lA = lds + b * ATILE + wr * (WM * 64);              // wave's A half
        const short* lB = lds + BM * 128 + b * 16384 + (wc >> 1) * 8192; // wave's B half
        const bool stA = (tt + 1 < NTt);
        const bool stB = (tt + 2 < NTt);

        // ===== half 1: stage A(tt+1); read af(qr0), bf0, bf1; MFMA (0,0),(0,1)
        if (stA) {
            STAGE_A8(0, kbase + tt + 1, bn);
            if constexpr (BM == 256) STAGE_A8(1, kbase + tt + 1, bn);
        }
#pragma unroll
        for (int t = 0; t < MQ; ++t) {
            const int rr = t * 16 + lm;
            const int x8 = rr & 7;
            af[t][0] = *reinterpret_cast<const short8*>(&lA[rr * 64 + ((q4 ^ x8) << 3)]);
            af[t][1] = *reinterpret_cast<const short8*>(&lA[rr * 64 + (((4 + q4) ^ x8) << 3)]);
        }
#pragma unroll
        for (int t = 0; t < 2; ++t) {
            const int rr = (wc & 1) * 64 + t * 16 + lm;
            const int x8 = rr & 7;
            bf0[t][0] = *reinterpret_cast<const short8*>(&lB[rr * 64 + ((q4 ^ x8) << 3)]);
            bf0[t][1] = *reinterpret_cast<const short8*>(&lB[rr * 64 + (((4 + q4) ^ x8) << 3)]);
        }
#pragma unroll
        for (int t = 0; t < 2; ++t) {
            const int rr = (wc & 1) * 64 + 32 + t * 16 + lm;
            const int x8 = rr & 7;
            bf1[t][0] = *reinterpret_cast<const short8*>(&lB[rr * 64 + ((q4 ^ x8) << 3)]);
            bf1[t][1] = *reinterpret_cast<const short8*>(&lB[rr * 64 + (((4 + q4) ^ x8) << 3)]);
        }
        __builtin_amdgcn_s_setprio(1);
#pragma unroll
        for (int t = 0; t < MQ; ++t)
#pragma unroll
            for (int u = 0; u < 2; ++u) {
                acc[0][0][t][u] = __builtin_amdgcn_mfma_f32_16x16x32_bf16(af[t][0], bf0[u][0], acc[0][0][t][u], 0, 0, 0);
                acc[0][0][t][u] = __builtin_amdgcn_mfma_f32_16x16x32_bf16(af[t][1], bf0[u][1], acc[0][0][t][u], 0, 0, 0);
            }
#pragma unroll
        for (int t = 0; t < MQ; ++t)
#pragma unroll
            for (int u = 0; u < 2; ++u) {
                acc[0][1][t][u] = __builtin_amdgcn_mfma_f32_16x16x32_bf16(af[t][0], bf1[u][0], acc[0][1][t][u], 0, 0, 0);
                acc[0][1][t][u] = __builtin_amdgcn_mfma_f32_16x16x32_bf16(af[t][1], bf1[u][1], acc[0][1][t][u], 0, 0, 0);
            }
        __builtin_amdgcn_s_setprio(0);
        __builtin_amdgcn_s_barrier();          // all waves' B[b] reads issued
        __builtin_amdgcn_sched_barrier(0);

        // ===== half 2: stage B(tt+2)->B[b]; read af(qr1); MFMA (1,0),(1,1)
        if (stB) {
            STAGE_B8(0, kbase + tt + 2, b);
            STAGE_B8(1, kbase + tt + 2, b);
        }
#pragma unroll
        for (int t = 0; t < MQ; ++t) {
            const int rr = MQ * 16 + t * 16 + lm;
            const int x8 = rr & 7;
            af[t][0] = *reinterpret_cast<const short8*>(&lA[rr * 64 + ((q4 ^ x8) << 3)]);
            af[t][1] = *reinterpret_cast<const short8*>(&lA[rr * 64 + (((4 + q4) ^ x8) << 3)]);
        }
        __builtin_amdgcn_s_setprio(1);
#pragma unroll
        for (int t = 0; t < MQ; ++t)
#pragma unroll
            for (int u = 0; u < 2; ++u) {
                acc[1][0][t][u] = __builtin_amdgcn_mfma_f32_16x16x32_bf16(af[t][0], bf0[u][0], acc[1][0][t][u], 0, 0, 0);
                acc[1][0][t][u] = __builtin_amdgcn_mfma_f32_16x16x32_bf16(af[t][1], bf0[u][1], acc[1][0][t][u], 0, 0, 0);
            }
#pragma unroll
        for (int t = 0; t < MQ; ++t)
#pragma unroll
            for (int u = 0; u < 2; ++u) {
                acc[1][1][t][u] = __builtin_amdgcn_mfma_f32_16x16x32_bf16(af[t][0], bf1[u][0], acc[1][1][t][u], 0, 0, 0);
                acc[1][1][t][u] = __builtin_amdgcn_mfma_f32_16x16x32_bf16(af[t][1], bf1[u][1], acc[1][1][t][u], 0, 0, 0);
            }
        __builtin_amdgcn_s_setprio(0);
        if (stB) {
            asm volatile("s_waitcnt vmcnt(4)" ::: "memory");   // A(tt+1),B(tt+1) landed
        } else if (stA) {
            asm volatile("s_waitcnt vmcnt(0)" ::: "memory");   // drain last A stage
        }
        __builtin_amdgcn_s_barrier();
        __builtin_amdgcn_sched_barrier(0);
    }
#undef STAGE_A8
#undef STAGE_B8

    // -------- epilogue
    const int rq = (lane >> 4) * 4;
#pragma unroll
    for (int qr = 0; qr < 2; ++qr)
#pragma unroll
    for (int qc = 0; qc < 2; ++qc)
#pragma unroll
    for (int t = 0; t < MQ; ++t)
#pragma unroll
    for (int u = 0; u < 2; ++u) {
        f32x4 v = acc[qr][qc][t][u];
        const int col = n0 + wc * 64 + qc * 32 + u * 16 + lm;
#pragma unroll
        for (int r = 0; r < 4; ++r) {
            const int row = m0 + wr * WM + qr * (WM / 2) + t * 16 + rq + r;
            if (mode == 0) {
                if (col < D_INNER) Cf[(size_t)row * D_INNER + col] = v[r];
                else               Cz[(size_t)row * D_INNER + (col - D_INNER)] = f2b(v[r]);
            } else {
                Cf[(size_t)blockIdx.z * 4096 * N + (size_t)row * N + col] = v[r];
            }
        }
    }
}

// ------------------------------------------------- out = x + P0 + P1 (out-proj reduce)
__global__ void k_reduce_out(const float* __restrict__ x, const float* __restrict__ P,
                             float* __restrict__ out) {
    int i = blockIdx.x * 256 + threadIdx.x;
    float4 a = reinterpret_cast<const float4*>(x)[i];
    float4 p = reinterpret_cast<const float4*>(P)[i];
    float4 q = reinterpret_cast<const float4*>(P + (size_t)4096 * 1024)[i];
    float4 o;
    o.x = a.x + p.x + q.x; o.y = a.y + p.y + q.y;
    o.z = a.z + p.z + q.z; o.w = a.w + p.w + q.w;
    reinterpret_cast<float4*>(out)[i] = o;
}

// ------------------------------------------------- causal depthwise conv + SiLU
__global__ void k_conv(const float* __restrict__ xc, const float* __restrict__ cw,
                       const float* __restrict__ cb, bf16* __restrict__ xcs) {
    size_t idx = (size_t)blockIdx.x * blockDim.x + threadIdx.x;
    int d = (int)(idx & (D_INNER - 1));
    int l = (int)((idx >> 11) & (SEQ - 1));
    float w0 = cw[d * 4 + 0], w1 = cw[d * 4 + 1];
    float w2 = cw[d * 4 + 2], w3 = cw[d * 4 + 3];
    const float* base = xc + idx;
    float acc = cb[d] + w3 * base[0];
    if (l >= 1) acc += w2 * base[-(int)D_INNER];
    if (l >= 2) acc += w1 * base[-2 * (int)D_INNER];
    if (l >= 3) acc += w0 * base[-3 * (int)D_INNER];
    xcs[idx] = f2b(acc / (1.f + __expf(-acc)));   // silu
}

// ------------------------------------------------- scan pass A: per-chunk partials
__global__ __launch_bounds__(256) void k_scan_partialB(
    const float* __restrict__ delta, const bf16* __restrict__ xcs,
    const float* __restrict__ xdbl, const float* __restrict__ A_log,
    bf16* __restrict__ chs, float* __restrict__ sumdl)
{
    __shared__ float Bsh[CHLEN][16];
    const int tid = threadIdx.x;
    const int d = blockIdx.x * 256 + tid;
    const int chunk = blockIdx.y;
    const int b = blockIdx.z;
    const size_t tbase = (size_t)b * SEQ + (size_t)chunk * CHLEN;

    if (tid < 128) {
        int t = tid >> 2, j = (tid & 3) * 4;
        float4 v = *reinterpret_cast<const float4*>(&xdbl[(tbase + t) * XDS + 64 + j]);
        *reinterpret_cast<float4*>(&Bsh[t][j]) = v;
    }
    float An[16];
#pragma unroll
    for (int j = 0; j < 4; ++j) {
        float4 v = *reinterpret_cast<const float4*>(&A_log[(size_t)d * DSTATE + j * 4]);
        An[j * 4 + 0] = -__expf(v.x); An[j * 4 + 1] = -__expf(v.y);
        An[j * 4 + 2] = -__expf(v.z); An[j * 4 + 3] = -__expf(v.w);
    }
    __syncthreads();

    float s[16];
#pragma unroll
    for (int n = 0; n < 16; ++n) s[n] = 0.f;
    float sd = 0.f;
    for (int t = 0; t < CHLEN; ++t) {
        size_t gt = tbase + t;
        float dl = delta[gt * D_INNER + d];
        float u  = b2f(xcs[gt * D_INNER + d]);
        float dlu = dl * u;
        sd += dl;
#pragma unroll
        for (int n = 0; n < 16; ++n) {
            float dA = __expf(dl * An[n]);
            s[n] = fmaf(dA, s[n], dlu * Bsh[t][n]);
        }
    }
    const int pair = b * D_INNER + d;
    bf16* co = chs + ((size_t)pair * NCH + chunk) * DSTATE;
#pragma unroll
    for (int n = 0; n < 16; ++n) co[n] = f2b(s[n]);
    sumdl[(size_t)pair * NCH + chunk] = sd;
}

// ------------------------------------------------- scan pass B: chunk-prefix combine
// sst ALIASES chs: read chunk-sum before writing entry state (same thread+element).
__global__ void k_scan_combineB(const bf16* __restrict__ chs, const float* __restrict__ sumdl,
                                const float* __restrict__ A_log, bf16* __restrict__ sst) {
    int idx = blockIdx.x * 256 + threadIdx.x;
    int pair = idx >> 4;
    int n = idx & 15;
    int d = pair & (D_INNER - 1);
    float An = -__expf(A_log[(size_t)d * DSTATE + n]);
    float s = 0.f;
    for (int c = 0; c < NCH; ++c) {
        size_t o = ((size_t)pair * NCH + c) * DSTATE + n;
        float loc = b2f(chs[o]);
        float ap = __expf(An * sumdl[(size_t)pair * NCH + c]);
        sst[o] = f2b(s);
        s = fmaf(ap, s, loc);
    }
}

// ------------------------------------------------- scan pass C: final y + gate
// yf aliases zbuf elementwise (same-thread read-then-write).
__global__ __launch_bounds__(256) void k_scan_finalB(
    const float* __restrict__ delta, const bf16* __restrict__ xcs,
    const float* __restrict__ xdbl, const bf16* __restrict__ zbuf,
    const float* __restrict__ A_log, const float* __restrict__ Dp,
    const bf16* __restrict__ sst, bf16* __restrict__ yf)
{
    __shared__ float BC[CHLEN][32];   // [t][0:16]=B, [t][16:32]=C
    const int tid = threadIdx.x;
    const int d = blockIdx.x * 256 + tid;
    const int chunk = blockIdx.y;
    const int b = blockIdx.z;
    const size_t tbase = (size_t)b * SEQ + (size_t)chunk * CHLEN;

    {
        int t = tid >> 3, j = (tid & 7) * 4;
        float4 v = *reinterpret_cast<const float4*>(&xdbl[(tbase + t) * XDS + 64 + j]);
        *reinterpret_cast<float4*>(&BC[t][j]) = v;
    }
    float An[16];
#pragma unroll
    for (int j = 0; j < 4; ++j) {
        float4 v = *reinterpret_cast<const float4*>(&A_log[(size_t)d * DSTATE + j * 4]);
        An[j * 4 + 0] = -__expf(v.x); An[j * 4 + 1] = -__expf(v.y);
        An[j * 4 + 2] = -__expf(v.z); An[j * 4 + 3] = -__expf(v.w);
    }
    const int pair = b * D_INNER + d;
    float s[16];
    const bf16* so = sst + ((size_t)pair * NCH + chunk) * DSTATE;
#pragma unroll
    for (int n = 0; n < 16; ++n) s[n] = b2f(so[n]);
    const float Dv = Dp[d];
    __syncthreads();

    for (int t = 0; t < CHLEN; ++t) {
        size_t gt = tbase + t;
        float dl = delta[gt * D_INNER + d];
        float u  = b2f(xcs[gt * D_INNER + d]);
        float dlu = dl * u;
        float y = 0.f;
#pragma unroll
        for (int n = 0; n < 16; ++n) {
            float dA = __expf(dl * An[n]);
            s[n] = fmaf(dA, s[n], dlu * BC[t][n]);
            y = fmaf(s[n], BC[t][16 + n], y);
        }
        float zv = b2f(zbuf[gt * D_INNER + d]);
        float sz = zv / (1.f + __expf(-zv));
        yf[gt * D_INNER + d] = f2b((y + u * Dv) * sz);
    }
}

// ---------------------------------------------------------------- launch
extern "C" void kernel_launch(void* const* d_in, const int* in_sizes, int n_in,
                              void* d_out, int out_size, void* d_ws, size_t ws_size,
                              hipStream_t stream) {
    const float* x      = (const float*)d_in[0];
    const float* ln_g   = (const float*)d_in[1];
    const float* ln_b   = (const float*)d_in[2];
    const float* W_in   = (const float*)d_in[3];
    const float* conv_w = (const float*)d_in[4];
    const float* conv_b = (const float*)d_in[5];
    const float* A_log  = (const float*)d_in[6];
    const float* D_par  = (const float*)d_in[7];
    const float* xpw    = (const float*)d_in[8];
    const float* dtw    = (const float*)d_in[9];
    const float* dtb    = (const float*)d_in[10];
    const float* W_out  = (const float*)d_in[11];
    float* out = (float*)d_out;

    char* ws = (char*)d_ws;
    // workspace (79,953,920 B), stage-lifetime aliased:
    //  [0,        8388608)  xn bf16 -> chs/sst bf16 (scan) -> wOutb bf16 (after scan_final)
    //  [8388608, 41943040)  xc fp32 -> xproj partials @8388608 (16.8MB, after conv)
    //                       -> delta fp32 -> P0 fp32 @8388608 + P1 fp32 @25165824
    //  [41943040,58720256)  z bf16  <- yf aliases z
    //  [58720256,75497472)  wInb bf16 -> xcs bf16
    //  [75497472,77594624)  xdbl fp32 (4096x128)
    //  [77594624,78643200)  sumdl; [78643200..] drb, dtwb, xpwb
    bf16*  xn    = (bf16*)(ws + 0);
    bf16*  chs   = (bf16*)(ws + 0);
    bf16*  sst   = chs;
    short* wOutb = (short*)(ws + 0);           // after scan kernels are done
    float* xc    = (float*)(ws + 8388608);
    float* Pxp   = (float*)(ws + 8388608);     // xproj partials (after conv consumed xc)
    float* delta = xc;
    float* P0    = (float*)(ws + 8388608);     // after delta is dead (post scan_final)
    bf16*  z     = (bf16*)(ws + 41943040);
    bf16*  yf    = z;
    short* wInb  = (short*)(ws + 58720256);
    bf16*  xcs   = (bf16*)(ws + 58720256);
    float* xdbl  = (float*)(ws + 75497472);
    float* sumdl = (float*)(ws + 77594624);
    short* drb   = (short*)(ws + 78643200);
    short* dtwb  = (short*)(ws + 79167488);
    short* xpwb  = (short*)(ws + 79429632);

    // fused prep: LN + f2b(W_in) + prep(xpw) + f2b(dtw)
    k_prep<<<8576, 256, 0, stream>>>(x, ln_g, ln_b, xn, W_in, wInb, xpw, xpwb, dtw, dtwb);
    // in-proj GEMM: 4096 x 4096 x 1024, relaxed 256^2 -> 256 blocks (1/CU)
    k_gemm8<256><<<dim3(4096 / 256, 4096 / 256, 1), 512, 0, stream>>>(
        (const short*)xn, wInb, 2 * D_INNER, D_MODEL, 0, xc, z);
    k_conv<<<(NTOK * D_INNER) / 256, 256, 0, stream>>>(xc, conv_w, conv_b, xcs);
    // xproj GEMM: 4096 x 128 x 2048, NT=64, split-K=8 partials -> 512 blocks + reduce
    k_gemm_mfma<64><<<dim3(2, 32, 8), 256, 0, stream>>>(
        (const short*)xcs, xpwb, XDS, D_INNER, 4, Pxp, nullptr, nullptr, nullptr, nullptr);
    k_xproj_red<<<(NTOK * 32) / 256, 256, 0, stream>>>(Pxp, drb, xdbl);
    // delta GEMM: 4096 x 2048 x 64, NT=64 -> 1024 blocks, softplus epilogue
    k_gemm_mfma<64><<<dim3(D_INNER / 64, 32, 1), 256, 0, stream>>>(
        drb, dtwb, D_INNER, DTRANK, 3, delta, nullptr, nullptr, nullptr, dtb);
    // selective scan (3-pass, register-state formulation)
    k_scan_partialB<<<dim3(D_INNER / 256, NCH, BSZ), 256, 0, stream>>>(
        delta, xcs, xdbl, A_log, chs, sumdl);
    k_scan_combineB<<<(NPAIR * DSTATE) / 256, 256, 0, stream>>>(chs, sumdl, A_log, sst);
    k_scan_finalB<<<dim3(D_INNER / 256, NCH, BSZ), 256, 0, stream>>>(
        delta, xcs, xdbl, z, A_log, D_par, sst, yf);
    // out-proj GEMM: 4096 x 1024 x 2048, relaxed 128x256 split-K=2 -> 256 blocks + reduce
    k_f2b<<<(D_MODEL * D_INNER / 4) / 256, 256, 0, stream>>>(W_out, wOutb);
    k_gemm8<128><<<dim3(D_MODEL / 256, 4096 / 128, 2), 512, 0, stream>>>(
        (const short*)yf, wOutb, D_MODEL, D_INNER, 4, P0, nullptr);
    k_reduce_out<<<(NTOK * D_MODEL / 4) / 256, 256, 0, stream>>>(x, P0, out);
}